// Round 6
// baseline (826.781 us; speedup 1.0000x reference)
//
#include <hip/hip_runtime.h>
#include <cstdint>
#include <cstddef>

typedef __bf16 bf16;
typedef __bf16 bf16x8 __attribute__((ext_vector_type(8)));
typedef __bf16 bf16x4 __attribute__((ext_vector_type(4)));
typedef float  f32x4  __attribute__((ext_vector_type(4)));

#define NB 7
static constexpr int Bq = 2, Sq = 4096, Dm = 1024, Dff = 4096;
static constexpr int Mrows = Bq * Sq;     // 8192
static constexpr int NCH = Sq / 4;        // 1024 chunks per (b,h)
static constexpr int CSW = 464;           // padded prefix-state row width

__device__ __forceinline__ void gload16(const void* g, void* l) {
  __builtin_amdgcn_global_load_lds((__attribute__((address_space(1))) void*)g,
                                   (__attribute__((address_space(3))) void*)l,
                                   16, 0, 0);
}

template <int N> __device__ __forceinline__ void wait_vmcnt() {
  asm volatile("s_waitcnt vmcnt(%0)" :: "n"(N) : "memory");
}
__device__ __forceinline__ void wait_lgkm0() {
  asm volatile("s_waitcnt lgkmcnt(0)" ::: "memory");
}
__device__ __forceinline__ void SB() { __builtin_amdgcn_sched_barrier(0); }

__device__ __forceinline__ float gelu_f(float x) {
  const float c = 0.79788456080286535588f;
  float z = c * (x + 0.044715f * x * x * x);
  float t = 1.f - 2.f / (__expf(2.f * z) + 1.f);   // tanh(z)
  return 0.5f * x * (1.f + t);
}

// ---------------- batched f32 -> bf16 convert (10 regions, 1 launch) ----------
struct CvtA {
  const float* s[10];
  bf16* d[10];
  int start[11];
};
__global__ __launch_bounds__(256) void cvt10(CvtA a) {
  const int i = blockIdx.x * 256 + threadIdx.x;
  int r = 0;
#pragma unroll
  for (int k = 1; k < 10; ++k) r += (i >= a.start[k]);
  const int o = i - a.start[r];
  f32x4 v = *(const f32x4*)&a.s[r][(size_t)o * 4];
  bf16x4 ov;
#pragma unroll
  for (int e = 0; e < 4; ++e) ov[e] = (bf16)v[e];
  *(bf16x4*)&a.d[r][(size_t)o * 4] = ov;
}

// ---------------- LayerNorm (ddof=1, /(std+eps)) -> bf16 ----------------
__global__ __launch_bounds__(256) void ln_kernel(const float* __restrict__ x,
                                                 const float* __restrict__ alpha,
                                                 const float* __restrict__ beta,
                                                 bf16* __restrict__ out) {
  const int row = blockIdx.x, tid = threadIdx.x;
  const float* xr = x + (size_t)row * Dm;
  f32x4 v = *(const f32x4*)&xr[tid * 4];
  float s  = v[0] + v[1] + v[2] + v[3];
  float s2 = v[0]*v[0] + v[1]*v[1] + v[2]*v[2] + v[3]*v[3];
#pragma unroll
  for (int o = 32; o > 0; o >>= 1) { s += __shfl_xor(s, o); s2 += __shfl_xor(s2, o); }
  __shared__ float red[8];
  const int wid = tid >> 6, lane = tid & 63;
  if (lane == 0) { red[wid] = s; red[wid + 4] = s2; }
  __syncthreads();
  s  = red[0] + red[1] + red[2] + red[3];
  s2 = red[4] + red[5] + red[6] + red[7];
  const float mean = s * (1.f / 1024.f);
  float var = (s2 - s * mean) * (1.f / 1023.f);
  var = fmaxf(var, 0.f);
  const float inv = 1.f / (sqrtf(var) + 1e-6f);
  f32x4 a4 = *(const f32x4*)&alpha[tid * 4];
  f32x4 b4 = *(const f32x4*)&beta[tid * 4];
  bf16x4 o4;
#pragma unroll
  for (int e = 0; e < 4; ++e) o4[e] = (bf16)(a4[e] * (v[e] - mean) * inv + b4[e]);
  *(bf16x4*)&out[(size_t)row * Dm + tid * 4] = o4;
}

// ============ 256x256 GEMM, one-barrier phases + cross-phase prefetch ============
// 512 thr, 8 waves (2m x 4n). Per phase: lgkm-wait(prefetched frags) -> issue
// next-phase ds_reads (LDS runs under MFMA) -> 16 MFMA -> stage half-tile ->
// barrier. vmcnt(2) at P4/P8 before next-buffer prefetch (vmcnt(0) at tail).
// SK=1: split-K over blockIdx.y (slice stride K elements along lda/ldb).
// MODE 0: out bf16 | 3: +bias,gelu->bf16
template <int MODE, int SK>
__global__ __launch_bounds__(512, 2) void gemm256(
    const bf16* __restrict__ A, int lda, const bf16* __restrict__ Bw, int ldb,
    int M, int N, int K,
    const float* __restrict__ bias, bf16* __restrict__ outB) {
  __shared__ __align__(16) bf16 As[2][256 * 64];   // 64 KB
  __shared__ __align__(16) bf16 Bs[2][256 * 64];   // 64 KB

  const int tid = threadIdx.x;
  const int lane = tid & 63, wid = tid >> 6;
  const int wm = wid >> 2, wn = wid & 3;

  if (SK) {
    const int ks = blockIdx.y;
    A    += (size_t)ks * K;
    Bw   += (size_t)ks * K;
    outB += (size_t)ks * M * N;
  }

  int bid = blockIdx.x;
  const int nwg = gridDim.x;
  bid = (bid & 7) * (nwg >> 3) + (bid >> 3);   // XCD swizzle (nwg % 8 == 0)
  const int nbx = N >> 8;
  const int bm = (bid / nbx) * 256, bn = (bid % nbx) * 256;
  const int NT = K >> 6, NI = NT >> 1;

  const int srow = tid >> 3;                       // 0..63
  const int scol = ((tid & 7) ^ (srow & 7)) * 8;   // inverse-swizzled k offset
  const bf16* Ag = A  + (size_t)(bm + srow) * lda + scol;
  const bf16* Bg = Bw + (size_t)(bn + srow) * ldb + scol;

  auto stA = [&](int buf, int H, int t) {
#pragma unroll
    for (int c = 0; c < 2; ++c)
      gload16(Ag + (size_t)(H * 128 + c * 64) * lda + (size_t)t * 64,
              (char*)(&As[buf][0]) + H * 16384 + c * 8192 + wid * 1024);
  };
  auto stB = [&](int buf, int H, int t) {
#pragma unroll
    for (int c = 0; c < 2; ++c)
      gload16(Bg + (size_t)(H * 128 + c * 64) * ldb + (size_t)t * 64,
              (char*)(&Bs[buf][0]) + H * 16384 + c * 8192 + wid * 1024);
  };

  f32x4 acc[8][4] = {};
  const int lr = lane & 15, uo = lane >> 4;

  bf16x8 A0[4][2], A1[4][2], B0[2][2], B1[2][2];

  auto ldA = [&](const bf16* Asb, int mh, bf16x8 (&a)[4][2]) {
#pragma unroll
    for (int i = 0; i < 4; ++i)
#pragma unroll
      for (int kh = 0; kh < 2; ++kh) {
        const int r = wm * 128 + mh * 64 + i * 16 + lr;
        const int u = (kh * 4 + uo) ^ (lr & 7);
        a[i][kh] = *(const bf16x8*)&Asb[r * 64 + u * 8];
      }
  };
  auto ldB = [&](const bf16* Bsb, int nh, bf16x8 (&b)[2][2]) {
#pragma unroll
    for (int j = 0; j < 2; ++j)
#pragma unroll
      for (int kh = 0; kh < 2; ++kh) {
        const int r = wn * 64 + nh * 32 + j * 16 + lr;
        const int u = (kh * 4 + uo) ^ (lr & 7);
        b[j][kh] = *(const bf16x8*)&Bsb[r * 64 + u * 8];
      }
  };
  auto mmq = [&](int mh, int nh, bf16x8 (&a)[4][2], bf16x8 (&b)[2][2]) {
    __builtin_amdgcn_s_setprio(1);
#pragma unroll
    for (int i = 0; i < 4; ++i)
#pragma unroll
      for (int j = 0; j < 2; ++j) {
        acc[mh*4+i][nh*2+j] = __builtin_amdgcn_mfma_f32_16x16x32_bf16(
            a[i][0], b[j][0], acc[mh*4+i][nh*2+j], 0, 0, 0);
        acc[mh*4+i][nh*2+j] = __builtin_amdgcn_mfma_f32_16x16x32_bf16(
            a[i][1], b[j][1], acc[mh*4+i][nh*2+j], 0, 0, 0);
      }
    __builtin_amdgcn_s_setprio(0);
  };

  // prologue: tile 0 full + tile 1 lo-halves staged; prefetch tile-0 frags
  stB(0, 0, 0); stB(0, 1, 0); stA(0, 0, 0); stA(0, 1, 0);
  stB(1, 0, 1); stA(1, 0, 1);
  wait_vmcnt<4>();                 // tile 0 fully in LDS
  __builtin_amdgcn_s_barrier();
  ldA(&As[0][0], 0, A0); ldB(&Bs[0][0], 0, B0);
  SB();

  for (int t = 0; t < NI; ++t) {
    const int u = 2 * t;
    const bool more = (t + 1 < NI);
#pragma unroll
    for (int hf = 0; hf < 2; ++hf) {
      const bf16* Asb = &As[hf][0];
      const bf16* Bsb = &Bs[hf][0];

      // ---- P1: Q(0,0) = A0 x B0 ; prefetch B1 ; stage Bhi ----
      wait_lgkm0(); SB();
      ldB(Bsb, 1, B1); SB();
      mmq(0, 0, A0, B0); SB();
      if (hf == 0) stB(1, 1, u + 1);
      else if (more) stB(0, 1, u + 2);
      SB(); __builtin_amdgcn_s_barrier(); SB();

      // ---- P2: Q(0,1) = A0 x B1 ; prefetch A1 ; stage Ahi ----
      wait_lgkm0(); SB();
      ldA(Asb, 1, A1); SB();
      mmq(0, 1, A0, B1); SB();
      if (hf == 0) stA(1, 1, u + 1);
      else if (more) stA(0, 1, u + 2);
      SB(); __builtin_amdgcn_s_barrier(); SB();

      // ---- P3: Q(1,0) = A1 x B0 ; stage Blo(next-next) ----
      wait_lgkm0(); SB();
      mmq(1, 0, A1, B0); SB();
      if (more) { if (hf == 0) stB(0, 0, u + 2); else stB(1, 0, u + 3); }
      SB(); __builtin_amdgcn_s_barrier(); SB();

      // ---- P4: Q(1,1) = A1 x B1 ; vmcnt; prefetch next-buf A0,B0 ; stage Alo ----
      if (!(hf == 1 && !more)) {
        if (hf == 0 && !more) wait_vmcnt<0>();
        else                  wait_vmcnt<2>();
        SB();
        ldA(&As[hf ^ 1][0], 0, A0);
        ldB(&Bs[hf ^ 1][0], 0, B0);
      }
      SB();
      mmq(1, 1, A1, B1); SB();
      if (more) { if (hf == 0) stA(0, 0, u + 2); else stA(1, 0, u + 3); }
      SB(); __builtin_amdgcn_s_barrier(); SB();
    }
  }

  // ---- epilogue ----
#pragma unroll
  for (int f = 0; f < 8; ++f) {
    const int r0 = bm + wm * 128 + f * 16 + (lane >> 4) * 4;
#pragma unroll
    for (int g = 0; g < 4; ++g) {
      const int c = bn + wn * 64 + g * 16 + (lane & 15);
      float bv = 0.f;
      if (MODE == 3) bv = bias[c];
#pragma unroll
      for (int r = 0; r < 4; ++r) {
        const size_t idx = (size_t)(r0 + r) * N + c;
        float v = acc[f][g][r];
        if (MODE == 3) v = gelu_f(v + bv);
        outB[idx] = (bf16)v;
      }
    }
  }
}

// ---------------- FFN2 split-K reduce: out = p0 + p1 + bias + res ----------------
__global__ __launch_bounds__(256) void ffn2red(
    const bf16* __restrict__ p0, const bf16* __restrict__ p1,
    const float* __restrict__ bias, const float* __restrict__ res,
    float* __restrict__ out) {
  const size_t i = ((size_t)blockIdx.x * 256 + threadIdx.x) * 8;
  bf16x8 a = *(const bf16x8*)&p0[i];
  bf16x8 b = *(const bf16x8*)&p1[i];
  f32x4 r0 = *(const f32x4*)&res[i];
  f32x4 r1 = *(const f32x4*)&res[i + 4];
  const int c = (int)(i & 1023);
  f32x4 o0, o1;
#pragma unroll
  for (int e = 0; e < 4; ++e) {
    o0[e] = (float)a[e] + (float)b[e] + bias[c + e] + r0[e];
    o1[e] = (float)a[4 + e] + (float)b[4 + e] + bias[c + 4 + e] + r1[e];
  }
  *(f32x4*)&out[i] = o0;
  *(f32x4*)&out[i + 4] = o1;
}

// ------------- 128x128 double-buffered GEMM, 256 threads, 2 blocks/CU -------------
// MODE 0: out bf16 | 1: +res(f32)->bf16 | 2: +res(f32)->f32
template <int MODE>
__global__ __launch_bounds__(256, 2) void gemm128(
    const bf16* __restrict__ A, const bf16* __restrict__ Bw,
    int M, int N, int K,
    const float* __restrict__ res,
    float* __restrict__ outF, bf16* __restrict__ outB) {
  constexpr int BM = 128, BN = 128;
  __shared__ __align__(16) bf16 As[2][BM * 64];   // 32 KB
  __shared__ __align__(16) bf16 Bs[2][BN * 64];   // 32 KB

  const int tid = threadIdx.x;
  const int lane = tid & 63, wid = tid >> 6;
  const int wm = wid >> 1, wn = wid & 1;

  int bid = blockIdx.x;
  const int nwg = gridDim.x;
  bid = (bid & 7) * (nwg >> 3) + (bid >> 3);
  const int nbx = N / BN;
  const int bm = (bid / nbx) * BM, bn = (bid % nbx) * BN;
  const int NT = K >> 6;

  const int srow = tid >> 3;
  const int scol = ((tid & 7) ^ (srow & 7)) * 8;
  const bf16* Ag = A  + (size_t)(bm + srow) * K + scol;
  const bf16* Bg = Bw + (size_t)(bn + srow) * K + scol;

  f32x4 acc[4][4] = {};
  const int lr = lane & 15, uo = lane >> 4;

  auto stA = [&](int buf, int t) {
#pragma unroll
    for (int c = 0; c < 4; ++c)
      gload16(Ag + ((size_t)(c * 32) * K + (size_t)t * 64),
              (char*)(&As[buf][0]) + c * 4096 + wid * 1024);
  };
  auto stB = [&](int buf, int t) {
#pragma unroll
    for (int c = 0; c < 4; ++c)
      gload16(Bg + ((size_t)(c * 32) * K + (size_t)t * 64),
              (char*)(&Bs[buf][0]) + c * 4096 + wid * 1024);
  };

  stA(0, 0); stB(0, 0);
  stA(1, 1); stB(1, 1);
  wait_vmcnt<8>();
  __builtin_amdgcn_s_barrier();

  bf16x8 a[4][2], b[4][2];

  for (int t = 0; t < NT; ++t) {
    const int cur = t & 1;
    const bf16* Asb = &As[cur][0];
    const bf16* Bsb = &Bs[cur][0];

#pragma unroll
    for (int i = 0; i < 4; ++i)
#pragma unroll
      for (int kh = 0; kh < 2; ++kh) {
        const int r = wm * 64 + i * 16 + lr;
        const int u = (kh * 4 + uo) ^ (lr & 7);
        a[i][kh] = *(const bf16x8*)&Asb[r * 64 + u * 8];
      }
#pragma unroll
    for (int j = 0; j < 4; ++j)
#pragma unroll
      for (int kh = 0; kh < 2; ++kh) {
        const int r = wn * 64 + j * 16 + lr;
        const int u = (kh * 4 + uo) ^ (lr & 7);
        b[j][kh] = *(const bf16x8*)&Bsb[r * 64 + u * 8];
      }
    wait_lgkm0();
    SB();
    __builtin_amdgcn_s_barrier();
    SB();

    if (t + 2 < NT) { stA(cur, t + 2); stB(cur, t + 2); }
    SB();

    __builtin_amdgcn_s_setprio(1);
#pragma unroll
    for (int i = 0; i < 4; ++i)
#pragma unroll
      for (int j = 0; j < 4; ++j) {
        acc[i][j] = __builtin_amdgcn_mfma_f32_16x16x32_bf16(a[i][0], b[j][0], acc[i][j], 0, 0, 0);
        acc[i][j] = __builtin_amdgcn_mfma_f32_16x16x32_bf16(a[i][1], b[j][1], acc[i][j], 0, 0, 0);
      }
    __builtin_amdgcn_s_setprio(0);
    SB();

    if (t < NT - 2) wait_vmcnt<8>();
    else            wait_vmcnt<0>();
    __builtin_amdgcn_s_barrier();
    SB();
  }

#pragma unroll
  for (int f = 0; f < 4; ++f) {
    const int r0 = bm + wm * 64 + f * 16 + (lane >> 4) * 4;
#pragma unroll
    for (int g = 0; g < 4; ++g) {
      const int c = bn + wn * 64 + g * 16 + (lane & 15);
#pragma unroll
      for (int r = 0; r < 4; ++r) {
        const size_t idx = (size_t)(r0 + r) * N + c;
        float v = acc[f][g][r];
        if (MODE == 1 || MODE == 2) v += res[idx];
        if (MODE == 0 || MODE == 1) outB[idx] = (bf16)v;
        else outF[idx] = v;
      }
    }
  }
}

// ------- fused Performer chunk-sums + segment scan (block = 1 segment) -------
__global__ __launch_bounds__(512) void perf_cs(
    const bf16* __restrict__ kmat, const bf16* __restrict__ vmat, int ld,
    const float* __restrict__ omega, float* __restrict__ CS,
    float* __restrict__ segtot) {
  const int tid = threadIdx.x;
  const int bh = blockIdx.y, b = bh >> 4, h = bh & 15;
  const int seg = blockIdx.x;
  const int s0 = seg * 512;
  __shared__ __align__(16) bf16 vs[512][64];   // XOR-swizzled, 64 KB
  __shared__ float kps[512][8];                // 16 KB
  __shared__ float oms[448];

  {
    const bf16* vb = vmat + ((size_t)(b * Sq + s0)) * ld + h * 64;
#pragma unroll
    for (int p = 0; p < 8; ++p) {
      const int row = p * 64 + (tid >> 3), c16 = (tid & 7) * 8;
      *(uint4*)&vs[row][c16 ^ ((row & 7) * 8)] =
          *(const uint4*)&vb[(size_t)row * ld + c16];
    }
  }
  if (tid < 448) oms[tid] = omega[tid];
  __syncthreads();

  {
    const int row = tid;
    const bf16* kr = kmat + ((size_t)(b * Sq + s0 + row)) * ld + h * 64;
    bf16x8 kv[8];
#pragma unroll
    for (int q = 0; q < 8; ++q) kv[q] = *(const bf16x8*)&kr[q * 8];
    float f[NB];
#pragma unroll
    for (int n = 0; n < NB; ++n) f[n] = 0.f;
#pragma unroll
    for (int d = 0; d < 64; ++d) {
      const float kd = (float)kv[d >> 3][d & 7];
#pragma unroll
      for (int n = 0; n < NB; ++n) f[n] += kd * oms[n * 64 + d];
    }
    float sum = 1e-6f, e[NB];
#pragma unroll
    for (int n = 0; n < NB; ++n) { e[n] = __expf(-0.5f * f[n] * f[n]); sum += e[n]; }
    const float inv = 1.f / sum;
#pragma unroll
    for (int n = 0; n < NB; ++n) kps[row][n] = e[n] * inv;
    kps[row][7] = 0.f;
  }
  __syncthreads();

  if (tid < CSW) {
    const int comp = tid;
    float* outb = CS + ((size_t)bh * NCH + seg * 128) * CSW;
    float r = 0.f;
    if (comp < 8) {
      for (int c = 0; c < 128; ++c) {
        if (comp < 7)
          r += kps[4*c][comp] + kps[4*c+1][comp] + kps[4*c+2][comp] + kps[4*c+3][comp];
        outb[(size_t)c * CSW + comp] = r;
      }
    } else if (comp < 456) {
      const int n = (comp - 8) >> 6, d = (comp - 8) & 63;
      for (int c = 0; c < 128; ++c) {
#pragma unroll
        for (int i = 0; i < 4; ++i) {
          const int row = 4 * c + i;
          r += kps[row][n] * (float)vs[row][d ^ ((row & 7) * 8)];
        }
        outb[(size_t)c * CSW + comp] = r;
      }
    } else {
      for (int c = 0; c < 128; ++c) outb[(size_t)c * CSW + comp] = 0.f;
    }
    segtot[((size_t)bh * 8 + seg) * CSW + comp] = r;
  }
}

// ---------------- exclusive scan of the 8 segment totals ----------------
__global__ __launch_bounds__(256) void perf_scan2(float* __restrict__ segtot) {
  const int bh = blockIdx.x;
  const int c0 = threadIdx.x;
  float run0 = 0.f, run1 = 0.f;
#pragma unroll
  for (int s = 0; s < 8; ++s) {
    float* st = segtot + ((size_t)bh * 8 + s) * CSW;
    float t0 = st[c0]; st[c0] = run0; run0 += t0;
    if (c0 + 256 < CSW) { float t1 = st[c0 + 256]; st[c0 + 256] = run1; run1 += t1; }
  }
}

// ---------------- Performer output ----------------
__global__ __launch_bounds__(256) void perf_out(
    const bf16* __restrict__ qmat, int ldq, const float* __restrict__ omega,
    const float* __restrict__ CS, const float* __restrict__ segtot,
    bf16* __restrict__ attn) {
  const int tid = threadIdx.x;
  const int bh = blockIdx.y, b = bh >> 4, h = bh & 15;
  const int s0 = blockIdx.x * 128;
  const int cg0 = s0 >> 2;
  const int seg = cg0 >> 7;
  __shared__ __align__(16) float Ps[32 * CSW];
  __shared__ float qps[128][8];
  __shared__ float oms[NB * 64];

  {
    const float* src = CS + ((size_t)bh * NCH + cg0) * CSW;
    const float* off = segtot + ((size_t)bh * 8 + seg) * CSW;
    for (int i = tid; i < 32 * CSW / 4; i += 256) {
      f32x4 a = *(const f32x4*)&src[i * 4];
      f32x4 o = *(const f32x4*)&off[(i % (CSW / 4)) * 4];
      a += o;
      *(f32x4*)&Ps[i * 4] = a;
    }
  }
  if (tid < 224) { oms[tid] = omega[tid]; oms[tid + 224] = omega[tid + 224]; }
  __syncthreads();
  {
    const int p = tid >> 1, half = tid & 1;
    const bf16* qr = qmat + ((size_t)(b * Sq + s0 + p)) * ldq + h * 64 + half * 32;
    bf16x8 qv[4];
#pragma unroll
    for (int q = 0; q < 4; ++q) qv[q] = *(const bf16x8*)&qr[q * 8];
    float f[NB];
#pragma unroll
    for (int n = 0; n < NB; ++n) f[n] = 0.f;
#pragma unroll
    for (int d = 0; d < 32; ++d) {
      float qd = (float)qv[d >> 3][d & 7];
#pragma unroll
      for (int n = 0; n < NB; ++n) f[n] += qd * oms[n * 64 + half * 32 + d];
    }
    float sum = 1e-6f;
    float e[NB];
#pragma unroll
    for (int n = 0; n < NB; ++n) {
      float full = f[n] + __shfl_xor(f[n], 1);
      e[n] = __expf(-0.5f * full * full);
      sum += e[n];
    }
    float inv = 1.f / sum;
    if (half == 0) {
      float den = 1e-6f;
      const float* Pr = &Ps[(p >> 2) * CSW];
#pragma unroll
      for (int n = 0; n < NB; ++n) {
        float qn = e[n] * inv;
        qps[p][n] = qn;
        den += qn * Pr[n];
      }
      qps[p][7] = 1.f / den;
    }
  }
  __syncthreads();
  {
    const int d = tid & 63, w = tid >> 6;
    for (int qq = w; qq < 128; qq += 4) {
      const float* Pr = &Ps[(qq >> 2) * CSW + 8 + d];
      float num = 0.f;
#pragma unroll
      for (int n = 0; n < NB; ++n) num += qps[qq][n] * Pr[n * 64];
      attn[((size_t)(b * Sq + s0 + qq)) * Dm + h * 64 + d] = (bf16)(num * qps[qq][7]);
    }
  }
}

// ---------------------------------------------------------------------------
extern "C" void kernel_launch(void* const* d_in, const int* in_sizes, int n_in,
                              void* d_out, int out_size, void* d_ws, size_t ws_size,
                              hipStream_t stream) {
  const float* x    = (const float*)d_in[0];
  const float* lto  = (const float*)d_in[1];
  const float* w_s[4] = {(const float*)d_in[2], (const float*)d_in[3],
                         (const float*)d_in[4], (const float*)d_in[5]};
  const float* w_c[4] = {(const float*)d_in[6], (const float*)d_in[7],
                         (const float*)d_in[8], (const float*)d_in[9]};
  const float* omega_s = (const float*)d_in[10];
  const float* omega_c = (const float*)d_in[11];
  const float* w1 = (const float*)d_in[12];
  const float* b1 = (const float*)d_in[13];
  const float* w2 = (const float*)d_in[14];
  const float* b2 = (const float*)d_in[15];
  const float* ln_a[3] = {(const float*)d_in[16], (const float*)d_in[18], (const float*)d_in[20]};
  const float* ln_b[3] = {(const float*)d_in[17], (const float*)d_in[19], (const float*)d_in[21]};

  char* ws = (char*)d_ws;
  size_t off = 0;
  auto alloc = [&](size_t bytes) -> char* {
    char* p = ws + off;
    off += (bytes + 255) & ~(size_t)255;
    return p;
  };

  const size_t actB = (size_t)Mrows * Dm * sizeof(bf16);     // 16 MiB
  const size_t MB32 = (size_t)Mrows * 2048 * sizeof(bf16);   // 32 MiB

  bf16* wqkv = (bf16*)alloc((size_t)3072 * 1024 * 2);
  bf16* wo_sb = (bf16*)alloc((size_t)1024 * 1024 * 2);
  bf16* wq_cb = (bf16*)alloc((size_t)1024 * 1024 * 2);
  bf16* wkv  = (bf16*)alloc((size_t)2048 * 1024 * 2);
  bf16* wo_cb = (bf16*)alloc((size_t)1024 * 1024 * 2);
  bf16* w1b = (bf16*)alloc((size_t)Dff * Dm * 2);
  bf16* w2b = (bf16*)alloc((size_t)Dff * Dm * 2);
  bf16* xnb  = (bf16*)alloc(actB);
  char* pool = alloc((size_t)Mrows * Dff * 2);               // 64 MiB shared pool
  bf16* qkvb = (bf16*)pool;                                  // 48 MiB (phase 1)
  bf16* kvb  = (bf16*)pool;                                  // 32 MiB (phase 2)
  bf16* qb   = (bf16*)(pool + MB32);                         // 16 MiB (phase 2)
  bf16* hb   = (bf16*)pool;                                  // 64 MiB (phase 3)
  bf16* attnb= (bf16*)alloc(actB);
  bf16* x2b  = (bf16*)alloc(actB);                           // adjacent to attnb
  bf16* ln1b = (bf16*)alloc(actB);
  float* lto2 = (float*)alloc((size_t)Mrows * Dm * 4);
  float* CSb  = (float*)alloc((size_t)32 * NCH * CSW * 4);
  float* stb  = (float*)alloc((size_t)32 * 8 * CSW * 4);
  bf16* fnb = xnb;    // xnb dead after QKV_s GEMM
  bf16* ppb = attnb;  // FFN2 split-K partials: attnb+x2b (32 MiB, dead by FFN2)

  // ---- batched weight conversion ----
  {
    CvtA a;
    const float* srcs[10] = {w_s[0], w_s[1], w_s[2], w_s[3], w_c[0],
                             w_c[1], w_c[2], w_c[3], w1, w2};
    bf16* dsts[10] = {wqkv, wqkv + 1048576, wqkv + 2097152, wo_sb, wq_cb,
                      wkv, wkv + 1048576, wo_cb, w1b, w2b};
    const int SM = 262144, LG = 1048576;
    int st = 0;
    for (int i = 0; i < 10; ++i) {
      a.s[i] = srcs[i]; a.d[i] = dsts[i]; a.start[i] = st;
      st += (i < 8) ? SM : LG;
    }
    a.start[10] = st;
    cvt10<<<st / 256, 256, 0, stream>>>(a);
  }

  dim3 gperf(Sq / 128, Bq * 16);
  dim3 gseg(8, Bq * 16);
  const int gQKV = (Mrows / 256) * (3072 / 256);   // 384
  const int gKV  = (Mrows / 256) * (2048 / 256);   // 256
  const int gFF1 = (Mrows / 256) * (4096 / 256);   // 512
  const int gN1k = (Mrows / 128) * (1024 / 128);   // 512

  // --- self performer on x ---
  ln_kernel<<<Mrows, 256, 0, stream>>>(x, ln_a[0], ln_b[0], xnb);
  gemm256<0, 0><<<gQKV, 512, 0, stream>>>(xnb, 1024, wqkv, 1024, Mrows, 3072, 1024, nullptr, qkvb);
  perf_cs<<<gseg, 512, 0, stream>>>(qkvb + 1024, qkvb + 2048, 3072, omega_s, CSb, stb);
  perf_scan2<<<32, 256, 0, stream>>>(stb);
  perf_out<<<gperf, 256, 0, stream>>>(qkvb, 3072, omega_s, CSb, stb, attnb);
  gemm128<1><<<gN1k, 256, 0, stream>>>(attnb, wo_sb, Mrows, 1024, 1024, x, nullptr, x2b);

  // --- cross performer: q from LN(lto), k/v from updated x ---
  ln_kernel<<<Mrows, 256, 0, stream>>>(lto, ln_a[1], ln_b[1], ln1b);
  gemm128<0><<<gN1k, 256, 0, stream>>>(ln1b, wq_cb, Mrows, 1024, 1024, nullptr, nullptr, qb);
  gemm256<0, 0><<<gKV, 512, 0, stream>>>(x2b, 1024, wkv, 1024, Mrows, 2048, 1024, nullptr, kvb);
  perf_cs<<<gseg, 512, 0, stream>>>(kvb, kvb + 1024, 2048, omega_c, CSb, stb);
  perf_scan2<<<32, 256, 0, stream>>>(stb);
  perf_out<<<gperf, 256, 0, stream>>>(qb, 1024, omega_c, CSb, stb, attnb);
  gemm128<2><<<gN1k, 256, 0, stream>>>(attnb, wo_cb, Mrows, 1024, 1024, lto, lto2, nullptr);

  // --- FFN ---
  ln_kernel<<<Mrows, 256, 0, stream>>>(lto2, ln_a[2], ln_b[2], fnb);
  gemm256<3, 0><<<gFF1, 512, 0, stream>>>(fnb, 1024, w1b, 1024, Mrows, 4096, 1024, b1, hb);
  gemm256<0, 1><<<dim3(128, 2), 512, 0, stream>>>(hb, 4096, w2b, 4096, Mrows, 1024, 2048, nullptr, ppb);
  ffn2red<<<Mrows * 1024 / 8 / 256, 256, 0, stream>>>(ppb, ppb + (size_t)Mrows * 1024, b2, lto2, (float*)d_out);
}

// Round 7
// 550.762 us; speedup vs baseline: 1.5012x; 1.5012x over previous
//
#include <hip/hip_runtime.h>
#include <cstdint>
#include <cstddef>

typedef __bf16 bf16;
typedef __bf16 bf16x8 __attribute__((ext_vector_type(8)));
typedef __bf16 bf16x4 __attribute__((ext_vector_type(4)));
typedef float  f32x4  __attribute__((ext_vector_type(4)));

#define NB 7
static constexpr int Bq = 2, Sq = 4096, Dm = 1024, Dff = 4096;
static constexpr int Mrows = Bq * Sq;     // 8192
static constexpr int NCH = Sq / 4;        // 1024 chunks per (b,h)
static constexpr int CSW = 464;           // padded prefix-state row width

__device__ __forceinline__ void gload16(const void* g, void* l) {
  __builtin_amdgcn_global_load_lds((__attribute__((address_space(1))) void*)g,
                                   (__attribute__((address_space(3))) void*)l,
                                   16, 0, 0);
}

template <int N> __device__ __forceinline__ void wait_vmcnt() {
  asm volatile("s_waitcnt vmcnt(%0)" :: "n"(N) : "memory");
}
template <int N> __device__ __forceinline__ void wait_lgkm() {
  asm volatile("s_waitcnt lgkmcnt(%0)" :: "n"(N) : "memory");
}
__device__ __forceinline__ void SB() { __builtin_amdgcn_sched_barrier(0); }

__device__ __forceinline__ float gelu_f(float x) {
  const float c = 0.79788456080286535588f;
  float z = c * (x + 0.044715f * x * x * x);
  float t = 1.f - 2.f / (__expf(2.f * z) + 1.f);   // tanh(z)
  return 0.5f * x * (1.f + t);
}

// ---------------- batched f32 -> bf16 convert (10 regions, 1 launch) ----------
struct CvtA {
  const float* s[10];
  bf16* d[10];
  int start[11];
};
__global__ __launch_bounds__(256) void cvt10(CvtA a) {
  const int i = blockIdx.x * 256 + threadIdx.x;
  int r = 0;
#pragma unroll
  for (int k = 1; k < 10; ++k) r += (i >= a.start[k]);
  const int o = i - a.start[r];
  f32x4 v = *(const f32x4*)&a.s[r][(size_t)o * 4];
  bf16x4 ov;
#pragma unroll
  for (int e = 0; e < 4; ++e) ov[e] = (bf16)v[e];
  *(bf16x4*)&a.d[r][(size_t)o * 4] = ov;
}

// ---------------- LayerNorm (ddof=1, /(std+eps)) -> bf16 ----------------
__global__ __launch_bounds__(256) void ln_kernel(const float* __restrict__ x,
                                                 const float* __restrict__ alpha,
                                                 const float* __restrict__ beta,
                                                 bf16* __restrict__ out) {
  const int row = blockIdx.x, tid = threadIdx.x;
  const float* xr = x + (size_t)row * Dm;
  f32x4 v = *(const f32x4*)&xr[tid * 4];
  float s  = v[0] + v[1] + v[2] + v[3];
  float s2 = v[0]*v[0] + v[1]*v[1] + v[2]*v[2] + v[3]*v[3];
#pragma unroll
  for (int o = 32; o > 0; o >>= 1) { s += __shfl_xor(s, o); s2 += __shfl_xor(s2, o); }
  __shared__ float red[8];
  const int wid = tid >> 6, lane = tid & 63;
  if (lane == 0) { red[wid] = s; red[wid + 4] = s2; }
  __syncthreads();
  s  = red[0] + red[1] + red[2] + red[3];
  s2 = red[4] + red[5] + red[6] + red[7];
  const float mean = s * (1.f / 1024.f);
  float var = (s2 - s * mean) * (1.f / 1023.f);
  var = fmaxf(var, 0.f);
  const float inv = 1.f / (sqrtf(var) + 1e-6f);
  f32x4 a4 = *(const f32x4*)&alpha[tid * 4];
  f32x4 b4 = *(const f32x4*)&beta[tid * 4];
  bf16x4 o4;
#pragma unroll
  for (int e = 0; e < 4; ++e) o4[e] = (bf16)(a4[e] * (v[e] - mean) * inv + b4[e]);
  *(bf16x4*)&out[(size_t)row * Dm + tid * 4] = o4;
}

// ============ 256x256 8-phase GEMM with progressive-lgkm MFMA overlap ============
// 512 thr, 8 waves (2m x 4n). Per phase: {ds_reads (B-group then A-pairs, order
// pinned) ; stage 1 half-tile ; barrier ; lgkmcnt(6/4/2/0)-interleaved MFMA groups
// ; barrier}. Stage map and vmcnt(4)@P4/P8 identical to the verified r4 schedule.
// SK=1: split-K over blockIdx.y. MODE 0: out bf16 | 3: +bias,gelu->bf16
template <int MODE, int SK>
__global__ __launch_bounds__(512, 2) void gemm256(
    const bf16* __restrict__ A, int lda, const bf16* __restrict__ Bw, int ldb,
    int M, int N, int K,
    const float* __restrict__ bias, bf16* __restrict__ outB) {
  __shared__ __align__(16) bf16 As[2][256 * 64];   // 64 KB
  __shared__ __align__(16) bf16 Bs[2][256 * 64];   // 64 KB

  const int tid = threadIdx.x;
  const int lane = tid & 63, wid = tid >> 6;
  const int wm = wid >> 2, wn = wid & 3;

  if (SK) {
    const int ks = blockIdx.y;
    A    += (size_t)ks * K;
    Bw   += (size_t)ks * K;
    outB += (size_t)ks * M * N;
  }

  int bid = blockIdx.x;
  const int nwg = gridDim.x;
  bid = (bid & 7) * (nwg >> 3) + (bid >> 3);   // XCD swizzle (nwg % 8 == 0)
  const int nbx = N >> 8;
  const int bm = (bid / nbx) * 256, bn = (bid % nbx) * 256;
  const int NT = K >> 6, NI = NT >> 1;

  const int srow = tid >> 3;                       // 0..63
  const int scol = ((tid & 7) ^ (srow & 7)) * 8;   // inverse-swizzled k offset
  const bf16* Ag = A  + (size_t)(bm + srow) * lda + scol;
  const bf16* Bg = Bw + (size_t)(bn + srow) * ldb + scol;

  auto stA = [&](int buf, int H, int t) {
#pragma unroll
    for (int c = 0; c < 2; ++c)
      gload16(Ag + (size_t)(H * 128 + c * 64) * lda + (size_t)t * 64,
              (char*)(&As[buf][0]) + H * 16384 + c * 8192 + wid * 1024);
  };
  auto stB = [&](int buf, int H, int t) {
#pragma unroll
    for (int c = 0; c < 2; ++c)
      gload16(Bg + (size_t)(H * 128 + c * 64) * ldb + (size_t)t * 64,
              (char*)(&Bs[buf][0]) + H * 16384 + c * 8192 + wid * 1024);
  };

  f32x4 acc[8][4] = {};
  const int lr = lane & 15, uo = lane >> 4;

  bf16x8 a[4][2], b0[2][2], b1[2][2];

  // B group: 4 ds_read_b128 (j0k0, j0k1, j1k0, j1k1)
  auto ldB = [&](const bf16* Bsb, int nh, bf16x8 (&b)[2][2]) {
#pragma unroll
    for (int j = 0; j < 2; ++j)
#pragma unroll
      for (int kh = 0; kh < 2; ++kh) {
        const int r = wn * 64 + nh * 32 + j * 16 + lr;
        const int u = (kh * 4 + uo) ^ (lr & 7);
        b[j][kh] = *(const bf16x8*)&Bsb[r * 64 + u * 8];
      }
  };
  // A pair: 2 ds_read_b128 for fragment i (kh 0,1)
  auto ldApair = [&](const bf16* Asb, int mh, int i) {
#pragma unroll
    for (int kh = 0; kh < 2; ++kh) {
      const int r = wm * 128 + mh * 64 + i * 16 + lr;
      const int u = (kh * 4 + uo) ^ (lr & 7);
      a[i][kh] = *(const bf16x8*)&Asb[r * 64 + u * 8];
    }
  };
  // 4 MFMA: fragment row i of quadrant (mh, nh)
  auto mm4 = [&](int mh, int nh, int i, bf16x8 (&b)[2][2]) {
    acc[mh*4+i][nh*2+0] = __builtin_amdgcn_mfma_f32_16x16x32_bf16(a[i][0], b[0][0], acc[mh*4+i][nh*2+0], 0, 0, 0);
    acc[mh*4+i][nh*2+0] = __builtin_amdgcn_mfma_f32_16x16x32_bf16(a[i][1], b[0][1], acc[mh*4+i][nh*2+0], 0, 0, 0);
    acc[mh*4+i][nh*2+1] = __builtin_amdgcn_mfma_f32_16x16x32_bf16(a[i][0], b[1][0], acc[mh*4+i][nh*2+1], 0, 0, 0);
    acc[mh*4+i][nh*2+1] = __builtin_amdgcn_mfma_f32_16x16x32_bf16(a[i][1], b[1][1], acc[mh*4+i][nh*2+1], 0, 0, 0);
  };
  // 8 MFMA: column j of quadrant (mh, nh), all i
  auto mm8j = [&](int mh, int nh, int j, bf16x8 (&b)[2][2]) {
#pragma unroll
    for (int i = 0; i < 4; ++i) {
      acc[mh*4+i][nh*2+j] = __builtin_amdgcn_mfma_f32_16x16x32_bf16(a[i][0], b[j][0], acc[mh*4+i][nh*2+j], 0, 0, 0);
      acc[mh*4+i][nh*2+j] = __builtin_amdgcn_mfma_f32_16x16x32_bf16(a[i][1], b[j][1], acc[mh*4+i][nh*2+j], 0, 0, 0);
    }
  };

  // prologue: tile 0 full + tile 1 lo-halves staged
  stB(0, 0, 0); stB(0, 1, 0); stA(0, 0, 0); stA(0, 1, 0);
  stB(1, 0, 1); stA(1, 0, 1);
  wait_vmcnt<4>();                 // tile 0 fully in LDS
  __builtin_amdgcn_s_barrier();

  for (int t = 0; t < NI; ++t) {
    const int u = 2 * t;
    const bool more = (t + 1 < NI);
#pragma unroll
    for (int hf = 0; hf < 2; ++hf) {
      const bf16* Asb = &As[hf][0];
      const bf16* Bsb = &Bs[hf][0];

      // ---- P1: Q(0,0). reads B0(4) + A0(8); stage Bhi ----
      ldB(Bsb, 0, b0); SB();
      ldApair(Asb, 0, 0); SB(); ldApair(Asb, 0, 1); SB();
      ldApair(Asb, 0, 2); SB(); ldApair(Asb, 0, 3); SB();
      if (hf == 0) stB(1, 1, u + 1);
      else if (more) stB(0, 1, u + 2);
      SB(); __builtin_amdgcn_s_barrier(); SB();
      wait_lgkm<6>(); SB(); __builtin_amdgcn_s_setprio(1);
      mm4(0, 0, 0, b0); SB();
      wait_lgkm<4>(); SB(); mm4(0, 0, 1, b0); SB();
      wait_lgkm<2>(); SB(); mm4(0, 0, 2, b0); SB();
      wait_lgkm<0>(); SB(); mm4(0, 0, 3, b0);
      __builtin_amdgcn_s_setprio(0); SB();
      __builtin_amdgcn_s_barrier(); SB();

      // ---- P2: Q(0,1). reads B1(4); stage Ahi ----
      ldB(Bsb, 1, b1); SB();
      if (hf == 0) stA(1, 1, u + 1);
      else if (more) stA(0, 1, u + 2);
      SB(); __builtin_amdgcn_s_barrier(); SB();
      wait_lgkm<2>(); SB(); __builtin_amdgcn_s_setprio(1);
      mm8j(0, 1, 0, b1); SB();
      wait_lgkm<0>(); SB(); mm8j(0, 1, 1, b1);
      __builtin_amdgcn_s_setprio(0); SB();
      __builtin_amdgcn_s_barrier(); SB();

      // ---- P3: Q(1,1). reads A1(8); stage Blo(next-next) ----
      ldApair(Asb, 1, 0); SB(); ldApair(Asb, 1, 1); SB();
      ldApair(Asb, 1, 2); SB(); ldApair(Asb, 1, 3); SB();
      if (more) { if (hf == 0) stB(0, 0, u + 2); else stB(1, 0, u + 3); }
      SB(); __builtin_amdgcn_s_barrier(); SB();
      wait_lgkm<6>(); SB(); __builtin_amdgcn_s_setprio(1);
      mm4(1, 1, 0, b1); SB();
      wait_lgkm<4>(); SB(); mm4(1, 1, 1, b1); SB();
      wait_lgkm<2>(); SB(); mm4(1, 1, 2, b1); SB();
      wait_lgkm<0>(); SB(); mm4(1, 1, 3, b1);
      __builtin_amdgcn_s_setprio(0); SB();
      __builtin_amdgcn_s_barrier(); SB();

      // ---- P4: Q(1,0). no reads; stage Alo; vmcnt boundary ----
      if (more) { if (hf == 0) stA(0, 0, u + 2); else stA(1, 0, u + 3); }
      SB(); __builtin_amdgcn_s_barrier(); SB();
      __builtin_amdgcn_s_setprio(1);
      mm4(1, 0, 0, b0); mm4(1, 0, 1, b0); mm4(1, 0, 2, b0); mm4(1, 0, 3, b0);
      __builtin_amdgcn_s_setprio(0); SB();
      if (hf == 0) { if (more) wait_vmcnt<4>(); else wait_vmcnt<0>(); }
      else if (more) wait_vmcnt<4>();
      __builtin_amdgcn_s_barrier(); SB();
    }
  }

  // ---- epilogue ----
#pragma unroll
  for (int f = 0; f < 8; ++f) {
    const int r0 = bm + wm * 128 + f * 16 + (lane >> 4) * 4;
#pragma unroll
    for (int g = 0; g < 4; ++g) {
      const int c = bn + wn * 64 + g * 16 + (lane & 15);
      float bv = 0.f;
      if (MODE == 3) bv = bias[c];
#pragma unroll
      for (int r = 0; r < 4; ++r) {
        const size_t idx = (size_t)(r0 + r) * N + c;
        float v = acc[f][g][r];
        if (MODE == 3) v = gelu_f(v + bv);
        outB[idx] = (bf16)v;
      }
    }
  }
}

// ---------------- FFN2 split-K reduce: out = p0 + p1 + bias + res ----------------
__global__ __launch_bounds__(256) void ffn2red(
    const bf16* __restrict__ p0, const bf16* __restrict__ p1,
    const float* __restrict__ bias, const float* __restrict__ res,
    float* __restrict__ out) {
  const size_t i = ((size_t)blockIdx.x * 256 + threadIdx.x) * 8;
  bf16x8 a = *(const bf16x8*)&p0[i];
  bf16x8 b = *(const bf16x8*)&p1[i];
  f32x4 r0 = *(const f32x4*)&res[i];
  f32x4 r1 = *(const f32x4*)&res[i + 4];
  const int c = (int)(i & 1023);
  f32x4 o0, o1;
#pragma unroll
  for (int e = 0; e < 4; ++e) {
    o0[e] = (float)a[e] + (float)b[e] + bias[c + e] + r0[e];
    o1[e] = (float)a[4 + e] + (float)b[4 + e] + bias[c + 4 + e] + r1[e];
  }
  *(f32x4*)&out[i] = o0;
  *(f32x4*)&out[i + 4] = o1;
}

// ------------- 128x128 double-buffered GEMM, 256 threads, 2 blocks/CU -------------
// MODE 0: out bf16 | 1: +res(f32)->bf16 | 2: +res(f32)->f32
template <int MODE>
__global__ __launch_bounds__(256, 2) void gemm128(
    const bf16* __restrict__ A, const bf16* __restrict__ Bw,
    int M, int N, int K,
    const float* __restrict__ res,
    float* __restrict__ outF, bf16* __restrict__ outB) {
  constexpr int BM = 128, BN = 128;
  __shared__ __align__(16) bf16 As[2][BM * 64];   // 32 KB
  __shared__ __align__(16) bf16 Bs[2][BN * 64];   // 32 KB

  const int tid = threadIdx.x;
  const int lane = tid & 63, wid = tid >> 6;
  const int wm = wid >> 1, wn = wid & 1;

  int bid = blockIdx.x;
  const int nwg = gridDim.x;
  bid = (bid & 7) * (nwg >> 3) + (bid >> 3);
  const int nbx = N / BN;
  const int bm = (bid / nbx) * BM, bn = (bid % nbx) * BN;
  const int NT = K >> 6;

  const int srow = tid >> 3;
  const int scol = ((tid & 7) ^ (srow & 7)) * 8;
  const bf16* Ag = A  + (size_t)(bm + srow) * K + scol;
  const bf16* Bg = Bw + (size_t)(bn + srow) * K + scol;

  f32x4 acc[4][4] = {};
  const int lr = lane & 15, uo = lane >> 4;

  auto stA = [&](int buf, int t) {
#pragma unroll
    for (int c = 0; c < 4; ++c)
      gload16(Ag + ((size_t)(c * 32) * K + (size_t)t * 64),
              (char*)(&As[buf][0]) + c * 4096 + wid * 1024);
  };
  auto stB = [&](int buf, int t) {
#pragma unroll
    for (int c = 0; c < 4; ++c)
      gload16(Bg + ((size_t)(c * 32) * K + (size_t)t * 64),
              (char*)(&Bs[buf][0]) + c * 4096 + wid * 1024);
  };

  stA(0, 0); stB(0, 0);
  stA(1, 1); stB(1, 1);
  wait_vmcnt<8>();
  __builtin_amdgcn_s_barrier();

  bf16x8 a[4][2], b[4][2];

  for (int t = 0; t < NT; ++t) {
    const int cur = t & 1;
    const bf16* Asb = &As[cur][0];
    const bf16* Bsb = &Bs[cur][0];

#pragma unroll
    for (int i = 0; i < 4; ++i)
#pragma unroll
      for (int kh = 0; kh < 2; ++kh) {
        const int r = wm * 64 + i * 16 + lr;
        const int u = (kh * 4 + uo) ^ (lr & 7);
        a[i][kh] = *(const bf16x8*)&Asb[r * 64 + u * 8];
      }
#pragma unroll
    for (int j = 0; j < 4; ++j)
#pragma unroll
      for (int kh = 0; kh < 2; ++kh) {
        const int r = wn * 64 + j * 16 + lr;
        const int u = (kh * 4 + uo) ^ (lr & 7);
        b[j][kh] = *(const bf16x8*)&Bsb[r * 64 + u * 8];
      }
    wait_lgkm<0>();
    SB();
    __builtin_amdgcn_s_barrier();
    SB();

    if (t + 2 < NT) { stA(cur, t + 2); stB(cur, t + 2); }
    SB();

    __builtin_amdgcn_s_setprio(1);
#pragma unroll
    for (int i = 0; i < 4; ++i)
#pragma unroll
      for (int j = 0; j < 4; ++j) {
        acc[i][j] = __builtin_amdgcn_mfma_f32_16x16x32_bf16(a[i][0], b[j][0], acc[i][j], 0, 0, 0);
        acc[i][j] = __builtin_amdgcn_mfma_f32_16x16x32_bf16(a[i][1], b[j][1], acc[i][j], 0, 0, 0);
      }
    __builtin_amdgcn_s_setprio(0);
    SB();

    if (t < NT - 2) wait_vmcnt<8>();
    else            wait_vmcnt<0>();
    __builtin_amdgcn_s_barrier();
    SB();
  }

#pragma unroll
  for (int f = 0; f < 4; ++f) {
    const int r0 = bm + wm * 64 + f * 16 + (lane >> 4) * 4;
#pragma unroll
    for (int g = 0; g < 4; ++g) {
      const int c = bn + wn * 64 + g * 16 + (lane & 15);
#pragma unroll
      for (int r = 0; r < 4; ++r) {
        const size_t idx = (size_t)(r0 + r) * N + c;
        float v = acc[f][g][r];
        if (MODE == 1 || MODE == 2) v += res[idx];
        if (MODE == 0 || MODE == 1) outB[idx] = (bf16)v;
        else outF[idx] = v;
      }
    }
  }
}

// ------- fused Performer chunk-sums + segment scan (block = 1 segment) -------
__global__ __launch_bounds__(512) void perf_cs(
    const bf16* __restrict__ kmat, const bf16* __restrict__ vmat, int ld,
    const float* __restrict__ omega, float* __restrict__ CS,
    float* __restrict__ segtot) {
  const int tid = threadIdx.x;
  const int bh = blockIdx.y, b = bh >> 4, h = bh & 15;
  const int seg = blockIdx.x;
  const int s0 = seg * 512;
  __shared__ __align__(16) bf16 vs[512][64];   // XOR-swizzled, 64 KB
  __shared__ float kps[512][8];                // 16 KB
  __shared__ float oms[448];

  {
    const bf16* vb = vmat + ((size_t)(b * Sq + s0)) * ld + h * 64;
#pragma unroll
    for (int p = 0; p < 8; ++p) {
      const int row = p * 64 + (tid >> 3), c16 = (tid & 7) * 8;
      *(uint4*)&vs[row][c16 ^ ((row & 7) * 8)] =
          *(const uint4*)&vb[(size_t)row * ld + c16];
    }
  }
  if (tid < 448) oms[tid] = omega[tid];
  __syncthreads();

  {
    const int row = tid;
    const bf16* kr = kmat + ((size_t)(b * Sq + s0 + row)) * ld + h * 64;
    bf16x8 kv[8];
#pragma unroll
    for (int q = 0; q < 8; ++q) kv[q] = *(const bf16x8*)&kr[q * 8];
    float f[NB];
#pragma unroll
    for (int n = 0; n < NB; ++n) f[n] = 0.f;
#pragma unroll
    for (int d = 0; d < 64; ++d) {
      const float kd = (float)kv[d >> 3][d & 7];
#pragma unroll
      for (int n = 0; n < NB; ++n) f[n] += kd * oms[n * 64 + d];
    }
    float sum = 1e-6f, e[NB];
#pragma unroll
    for (int n = 0; n < NB; ++n) { e[n] = __expf(-0.5f * f[n] * f[n]); sum += e[n]; }
    const float inv = 1.f / sum;
#pragma unroll
    for (int n = 0; n < NB; ++n) kps[row][n] = e[n] * inv;
    kps[row][7] = 0.f;
  }
  __syncthreads();

  if (tid < CSW) {
    const int comp = tid;
    float* outb = CS + ((size_t)bh * NCH + seg * 128) * CSW;
    float r = 0.f;
    if (comp < 8) {
      for (int c = 0; c < 128; ++c) {
        if (comp < 7)
          r += kps[4*c][comp] + kps[4*c+1][comp] + kps[4*c+2][comp] + kps[4*c+3][comp];
        outb[(size_t)c * CSW + comp] = r;
      }
    } else if (comp < 456) {
      const int n = (comp - 8) >> 6, d = (comp - 8) & 63;
      for (int c = 0; c < 128; ++c) {
#pragma unroll
        for (int i = 0; i < 4; ++i) {
          const int row = 4 * c + i;
          r += kps[row][n] * (float)vs[row][d ^ ((row & 7) * 8)];
        }
        outb[(size_t)c * CSW + comp] = r;
      }
    } else {
      for (int c = 0; c < 128; ++c) outb[(size_t)c * CSW + comp] = 0.f;
    }
    segtot[((size_t)bh * 8 + seg) * CSW + comp] = r;
  }
}

// ---------------- exclusive scan of the 8 segment totals ----------------
__global__ __launch_bounds__(256) void perf_scan2(float* __restrict__ segtot) {
  const int bh = blockIdx.x;
  const int c0 = threadIdx.x;
  float run0 = 0.f, run1 = 0.f;
#pragma unroll
  for (int s = 0; s < 8; ++s) {
    float* st = segtot + ((size_t)bh * 8 + s) * CSW;
    float t0 = st[c0]; st[c0] = run0; run0 += t0;
    if (c0 + 256 < CSW) { float t1 = st[c0 + 256]; st[c0 + 256] = run1; run1 += t1; }
  }
}

// ---------------- Performer output ----------------
__global__ __launch_bounds__(256) void perf_out(
    const bf16* __restrict__ qmat, int ldq, const float* __restrict__ omega,
    const float* __restrict__ CS, const float* __restrict__ segtot,
    bf16* __restrict__ attn) {
  const int tid = threadIdx.x;
  const int bh = blockIdx.y, b = bh >> 4, h = bh & 15;
  const int s0 = blockIdx.x * 128;
  const int cg0 = s0 >> 2;
  const int seg = cg0 >> 7;
  __shared__ __align__(16) float Ps[32 * CSW];
  __shared__ float qps[128][8];
  __shared__ float oms[NB * 64];

  {
    const float* src = CS + ((size_t)bh * NCH + cg0) * CSW;
    const float* off = segtot + ((size_t)bh * 8 + seg) * CSW;
    for (int i = tid; i < 32 * CSW / 4; i += 256) {
      f32x4 a = *(const f32x4*)&src[i * 4];
      f32x4 o = *(const f32x4*)&off[(i % (CSW / 4)) * 4];
      a += o;
      *(f32x4*)&Ps[i * 4] = a;
    }
  }
  if (tid < 224) { oms[tid] = omega[tid]; oms[tid + 224] = omega[tid + 224]; }
  __syncthreads();
  {
    const int p = tid >> 1, half = tid & 1;
    const bf16* qr = qmat + ((size_t)(b * Sq + s0 + p)) * ldq + h * 64 + half * 32;
    bf16x8 qv[4];
#pragma unroll
    for (int q = 0; q < 4; ++q) qv[q] = *(const bf16x8*)&qr[q * 8];
    float f[NB];
#pragma unroll
    for (int n = 0; n < NB; ++n) f[n] = 0.f;
#pragma unroll
    for (int d = 0; d < 32; ++d) {
      float qd = (float)qv[d >> 3][d & 7];
#pragma unroll
      for (int n = 0; n < NB; ++n) f[n] += qd * oms[n * 64 + half * 32 + d];
    }
    float sum = 1e-6f;
    float e[NB];
#pragma unroll
    for (int n = 0; n < NB; ++n) {
      float full = f[n] + __shfl_xor(f[n], 1);
      e[n] = __expf(-0.5f * full * full);
      sum += e[n];
    }
    float inv = 1.f / sum;
    if (half == 0) {
      float den = 1e-6f;
      const float* Pr = &Ps[(p >> 2) * CSW];
#pragma unroll
      for (int n = 0; n < NB; ++n) {
        float qn = e[n] * inv;
        qps[p][n] = qn;
        den += qn * Pr[n];
      }
      qps[p][7] = 1.f / den;
    }
  }
  __syncthreads();
  {
    const int d = tid & 63, w = tid >> 6;
    for (int qq = w; qq < 128; qq += 4) {
      const float* Pr = &Ps[(qq >> 2) * CSW + 8 + d];
      float num = 0.f;
#pragma unroll
      for (int n = 0; n < NB; ++n) num += qps[qq][n] * Pr[n * 64];
      attn[((size_t)(b * Sq + s0 + qq)) * Dm + h * 64 + d] = (bf16)(num * qps[qq][7]);
    }
  }
}

// ---------------------------------------------------------------------------
extern "C" void kernel_launch(void* const* d_in, const int* in_sizes, int n_in,
                              void* d_out, int out_size, void* d_ws, size_t ws_size,
                              hipStream_t stream) {
  const float* x    = (const float*)d_in[0];
  const float* lto  = (const float*)d_in[1];
  const float* w_s[4] = {(const float*)d_in[2], (const float*)d_in[3],
                         (const float*)d_in[4], (const float*)d_in[5]};
  const float* w_c[4] = {(const float*)d_in[6], (const float*)d_in[7],
                         (const float*)d_in[8], (const float*)d_in[9]};
  const float* omega_s = (const float*)d_in[10];
  const float* omega_c = (const float*)d_in[11];
  const float* w1 = (const float*)d_in[12];
  const float* b1 = (const float*)d_in[13];
  const float* w2 = (const float*)d_in[14];
  const float* b2 = (const float*)d_in[15];
  const float* ln_a[3] = {(const float*)d_in[16], (const float*)d_in[18], (const float*)d_in[20]};
  const float* ln_b[3] = {(const float*)d_in[17], (const float*)d_in[19], (const float*)d_in[21]};

  char* ws = (char*)d_ws;
  size_t off = 0;
  auto alloc = [&](size_t bytes) -> char* {
    char* p = ws + off;
    off += (bytes + 255) & ~(size_t)255;
    return p;
  };

  const size_t actB = (size_t)Mrows * Dm * sizeof(bf16);     // 16 MiB
  const size_t MB32 = (size_t)Mrows * 2048 * sizeof(bf16);   // 32 MiB

  bf16* wqkv = (bf16*)alloc((size_t)3072 * 1024 * 2);
  bf16* wo_sb = (bf16*)alloc((size_t)1024 * 1024 * 2);
  bf16* wq_cb = (bf16*)alloc((size_t)1024 * 1024 * 2);
  bf16* wkv  = (bf16*)alloc((size_t)2048 * 1024 * 2);
  bf16* wo_cb = (bf16*)alloc((size_t)1024 * 1024 * 2);
  bf16* w1b = (bf16*)alloc((size_t)Dff * Dm * 2);
  bf16* w2b = (bf16*)alloc((size_t)Dff * Dm * 2);
  bf16* xnb  = (bf16*)alloc(actB);
  char* pool = alloc((size_t)Mrows * Dff * 2);               // 64 MiB shared pool
  bf16* qkvb = (bf16*)pool;                                  // 48 MiB (phase 1)
  bf16* kvb  = (bf16*)pool;                                  // 32 MiB (phase 2)
  bf16* qb   = (bf16*)(pool + MB32);                         // 16 MiB (phase 2)
  bf16* hb   = (bf16*)pool;                                  // 64 MiB (phase 3)
  bf16* attnb= (bf16*)alloc(actB);
  bf16* x2b  = (bf16*)alloc(actB);                           // adjacent to attnb
  bf16* ln1b = (bf16*)alloc(actB);
  float* lto2 = (float*)alloc((size_t)Mrows * Dm * 4);
  float* CSb  = (float*)alloc((size_t)32 * NCH * CSW * 4);
  float* stb  = (float*)alloc((size_t)32 * 8 * CSW * 4);
  bf16* fnb = xnb;    // xnb dead after QKV_s GEMM
  bf16* ppb = attnb;  // FFN2 split-K partials: attnb+x2b (32 MiB, dead by FFN2)

  // ---- batched weight conversion ----
  {
    CvtA a;
    const float* srcs[10] = {w_s[0], w_s[1], w_s[2], w_s[3], w_c[0],
                             w_c[1], w_c[2], w_c[3], w1, w2};
    bf16* dsts[10] = {wqkv, wqkv + 1048576, wqkv + 2097152, wo_sb, wq_cb,
                      wkv, wkv + 1048576, wo_cb, w1b, w2b};
    const int SM = 262144, LG = 1048576;
    int st = 0;
    for (int i = 0; i < 10; ++i) {
      a.s[i] = srcs[i]; a.d[i] = dsts[i]; a.start[i] = st;
      st += (i < 8) ? SM : LG;
    }
    a.start[10] = st;
    cvt10<<<st / 256, 256, 0, stream>>>(a);
  }

  dim3 gperf(Sq / 128, Bq * 16);
  dim3 gseg(8, Bq * 16);
  const int gQKV = (Mrows / 256) * (3072 / 256);   // 384
  const int gKV  = (Mrows / 256) * (2048 / 256);   // 256
  const int gFF1 = (Mrows / 256) * (4096 / 256);   // 512
  const int gN1k = (Mrows / 128) * (1024 / 128);   // 512

  // --- self performer on x ---
  ln_kernel<<<Mrows, 256, 0, stream>>>(x, ln_a[0], ln_b[0], xnb);
  gemm256<0, 0><<<gQKV, 512, 0, stream>>>(xnb, 1024, wqkv, 1024, Mrows, 3072, 1024, nullptr, qkvb);
  perf_cs<<<gseg, 512, 0, stream>>>(qkvb + 1024, qkvb + 2048, 3072, omega_s, CSb, stb);
  perf_scan2<<<32, 256, 0, stream>>>(stb);
  perf_out<<<gperf, 256, 0, stream>>>(qkvb, 3072, omega_s, CSb, stb, attnb);
  gemm128<1><<<gN1k, 256, 0, stream>>>(attnb, wo_sb, Mrows, 1024, 1024, x, nullptr, x2b);

  // --- cross performer: q from LN(lto), k/v from updated x ---
  ln_kernel<<<Mrows, 256, 0, stream>>>(lto, ln_a[1], ln_b[1], ln1b);
  gemm128<0><<<gN1k, 256, 0, stream>>>(ln1b, wq_cb, Mrows, 1024, 1024, nullptr, nullptr, qb);
  gemm256<0, 0><<<gKV, 512, 0, stream>>>(x2b, 1024, wkv, 1024, Mrows, 2048, 1024, nullptr, kvb);
  perf_cs<<<gseg, 512, 0, stream>>>(kvb, kvb + 1024, 2048, omega_c, CSb, stb);
  perf_scan2<<<32, 256, 0, stream>>>(stb);
  perf_out<<<gperf, 256, 0, stream>>>(qb, 1024, omega_c, CSb, stb, attnb);
  gemm128<2><<<gN1k, 256, 0, stream>>>(attnb, wo_cb, Mrows, 1024, 1024, lto, lto2, nullptr);

  // --- FFN ---
  ln_kernel<<<Mrows, 256, 0, stream>>>(lto2, ln_a[2], ln_b[2], fnb);
  gemm256<3, 0><<<gFF1, 512, 0, stream>>>(fnb, 1024, w1b, 1024, Mrows, 4096, 1024, b1, hb);
  gemm256<0, 1><<<dim3(128, 2), 512, 0, stream>>>(hb, 4096, w2b, 4096, Mrows, 1024, 2048, nullptr, ppb);
  ffn2red<<<Mrows * 1024 / 8 / 256, 256, 0, stream>>>(ppb, ppb + (size_t)Mrows * 1024, b2, lto2, (float*)d_out);
}

// Round 8
// 521.804 us; speedup vs baseline: 1.5845x; 1.0555x over previous
//
#include <hip/hip_runtime.h>
#include <cstdint>
#include <cstddef>

typedef __bf16 bf16;
typedef __bf16 bf16x8 __attribute__((ext_vector_type(8)));
typedef __bf16 bf16x4 __attribute__((ext_vector_type(4)));
typedef float  f32x4  __attribute__((ext_vector_type(4)));

#define NB 7
static constexpr int Bq = 2, Sq = 4096, Dm = 1024, Dff = 4096;
static constexpr int Mrows = Bq * Sq;     // 8192
static constexpr int NCH = Sq / 4;        // 1024 chunks per (b,h)
static constexpr int CSW = 464;           // padded prefix-state row width

template <int V> struct ic { static constexpr int value = V; };

__device__ __forceinline__ void gload16(const void* g, void* l) {
  __builtin_amdgcn_global_load_lds((__attribute__((address_space(1))) void*)g,
                                   (__attribute__((address_space(3))) void*)l,
                                   16, 0, 0);
}

template <int N> __device__ __forceinline__ void wait_vmcnt() {
  asm volatile("s_waitcnt vmcnt(%0)" :: "n"(N) : "memory");
}
__device__ __forceinline__ void wait_lgkm0() {
  asm volatile("s_waitcnt lgkmcnt(0)" ::: "memory");
}
__device__ __forceinline__ void SB() { __builtin_amdgcn_sched_barrier(0); }

__device__ __forceinline__ float gelu_f(float x) {
  const float c = 0.79788456080286535588f;
  float z = c * (x + 0.044715f * x * x * x);
  float t = 1.f - 2.f / (__expf(2.f * z) + 1.f);   // tanh(z)
  return 0.5f * x * (1.f + t);
}

// ---------------- batched f32 -> bf16 convert (10 regions, 1 launch) ----------
struct CvtA {
  const float* s[10];
  bf16* d[10];
  int start[11];
};
__global__ __launch_bounds__(256) void cvt10(CvtA a) {
  const int i = blockIdx.x * 256 + threadIdx.x;
  int r = 0;
#pragma unroll
  for (int k = 1; k < 10; ++k) r += (i >= a.start[k]);
  const int o = i - a.start[r];
  f32x4 v = *(const f32x4*)&a.s[r][(size_t)o * 4];
  bf16x4 ov;
#pragma unroll
  for (int e = 0; e < 4; ++e) ov[e] = (bf16)v[e];
  *(bf16x4*)&a.d[r][(size_t)o * 4] = ov;
}

// ---------------- LayerNorm (ddof=1, /(std+eps)) -> bf16 ----------------
__global__ __launch_bounds__(256) void ln_kernel(const float* __restrict__ x,
                                                 const float* __restrict__ alpha,
                                                 const float* __restrict__ beta,
                                                 bf16* __restrict__ out) {
  const int row = blockIdx.x, tid = threadIdx.x;
  const float* xr = x + (size_t)row * Dm;
  f32x4 v = *(const f32x4*)&xr[tid * 4];
  float s  = v[0] + v[1] + v[2] + v[3];
  float s2 = v[0]*v[0] + v[1]*v[1] + v[2]*v[2] + v[3]*v[3];
#pragma unroll
  for (int o = 32; o > 0; o >>= 1) { s += __shfl_xor(s, o); s2 += __shfl_xor(s2, o); }
  __shared__ float red[8];
  const int wid = tid >> 6, lane = tid & 63;
  if (lane == 0) { red[wid] = s; red[wid + 4] = s2; }
  __syncthreads();
  s  = red[0] + red[1] + red[2] + red[3];
  s2 = red[4] + red[5] + red[6] + red[7];
  const float mean = s * (1.f / 1024.f);
  float var = (s2 - s * mean) * (1.f / 1023.f);
  var = fmaxf(var, 0.f);
  const float inv = 1.f / (sqrtf(var) + 1e-6f);
  f32x4 a4 = *(const f32x4*)&alpha[tid * 4];
  f32x4 b4 = *(const f32x4*)&beta[tid * 4];
  bf16x4 o4;
#pragma unroll
  for (int e = 0; e < 4; ++e) o4[e] = (bf16)(a4[e] * (v[e] - mean) * inv + b4[e]);
  *(bf16x4*)&out[(size_t)row * Dm + tid * 4] = o4;
}

// ------------- 128x128 double-buffered GEMM, 256 threads, 2 blocks/CU -------------
// r4 schedule (proven) + zero per-tile address VALU: K-loop unrolled x2 so the
// buffer index is compile-time; all ds_reads use 4 precomputed per-lane byte
// offsets + constexpr `offset:` immediates; staging sources are two running
// pointers (+64 elem/tile). LDS: A bufs @0/16384, B bufs @32768/49152 (64 KB).
// MODE 0: out bf16 | 1: +res(f32)->bf16 | 2: +res(f32)->f32 | 3: +bias,gelu->bf16
// MODE 4: +bias+res(f32)->f32
template <int MODE>
__global__ __launch_bounds__(256, 2) void gemm128(
    const bf16* __restrict__ A, const bf16* __restrict__ Bw,
    int M, int N, int K,
    const float* __restrict__ bias, const float* __restrict__ res,
    float* __restrict__ outF, bf16* __restrict__ outB) {
  __shared__ __align__(16) char lds[65536];

  const int tid = threadIdx.x;
  const int lane = tid & 63, wid = tid >> 6;
  const int wm = wid >> 1, wn = wid & 1;

  int bid = blockIdx.x;
  const int nwg = gridDim.x;
  bid = (bid & 7) * (nwg >> 3) + (bid >> 3);   // XCD swizzle (nwg % 8 == 0)
  const int nbx = N >> 7;
  const int bm = (bid / nbx) * 128, bn = (bid % nbx) * 128;
  const int NT = K >> 6;                       // always even (K = 1024/2048/4096)

  // ---- staging: global sources (pre-swizzled k offset), LDS dests ----
  const int srow = tid >> 3;                       // 0..31
  const int scol = ((tid & 7) ^ (srow & 7)) * 8;   // inverse-swizzled k offset
  const bf16* pSA = A  + (size_t)(bm + srow) * K + scol;   // tile 0 source
  const bf16* pSB = Bw + (size_t)(bn + srow) * K + scol;
  const size_t cK = (size_t)32 * K;                // row-chunk stride (elements)
  const int stDa = wid * 1024;                     // LDS dest base (wave-uniform)

  auto stage = [&](int buf, const bf16* sa, const bf16* sb) {
#pragma unroll
    for (int c = 0; c < 4; ++c) {
      gload16(sa + (size_t)c * cK, &lds[buf * 16384 + c * 4096 + stDa]);
      gload16(sb + (size_t)c * cK, &lds[32768 + buf * 16384 + c * 4096 + stDa]);
    }
  };

  // ---- LDS read base offsets (per-lane, loop-invariant) ----
  const int lr = lane & 15, uo = lane >> 4;
  const int rdA0 = (wm * 64 + lr) * 128 + ((uo)     ^ (lr & 7)) * 16;   // kh=0
  const int rdA1 = (wm * 64 + lr) * 128 + ((4 + uo) ^ (lr & 7)) * 16;   // kh=1
  const int rdB0 = 32768 + (wn * 64 + lr) * 128 + ((uo)     ^ (lr & 7)) * 16;
  const int rdB1 = 32768 + (wn * 64 + lr) * 128 + ((4 + uo) ^ (lr & 7)) * 16;

  f32x4 acc[4][4] = {};
  bf16x8 a[4][2], b[4][2];

  // prologue: stage tiles 0 and 1
  stage(0, pSA, pSB);
  stage(1, pSA + 64, pSB + 64);
  pSA += 128; pSB += 128;            // now points at tile-2 source
  wait_vmcnt<8>();                   // tile 0 fully in LDS
  __builtin_amdgcn_s_barrier();

  // one K-tile: reads (const offsets) -> lgkm0 -> barrier -> stage(t+2) ->
  // 32 MFMA -> vmcnt(8)/(0) -> barrier
  auto TILE = [&](auto BUFC, int tt) {
    constexpr int BUF = decltype(BUFC)::value;
#pragma unroll
    for (int i = 0; i < 4; ++i) {
      a[i][0] = *(const bf16x8*)&lds[rdA0 + BUF * 16384 + i * 2048];
      a[i][1] = *(const bf16x8*)&lds[rdA1 + BUF * 16384 + i * 2048];
    }
#pragma unroll
    for (int j = 0; j < 4; ++j) {
      b[j][0] = *(const bf16x8*)&lds[rdB0 + BUF * 16384 + j * 2048];
      b[j][1] = *(const bf16x8*)&lds[rdB1 + BUF * 16384 + j * 2048];
    }
    wait_lgkm0(); SB();
    __builtin_amdgcn_s_barrier(); SB();

    if (tt + 2 < NT) stage(BUF, pSA + (size_t)(tt & 1) * 64,
                                pSB + (size_t)(tt & 1) * 64);
    SB();
    __builtin_amdgcn_s_setprio(1);
#pragma unroll
    for (int i = 0; i < 4; ++i)
#pragma unroll
      for (int j = 0; j < 4; ++j) {
        acc[i][j] = __builtin_amdgcn_mfma_f32_16x16x32_bf16(a[i][0], b[j][0], acc[i][j], 0, 0, 0);
        acc[i][j] = __builtin_amdgcn_mfma_f32_16x16x32_bf16(a[i][1], b[j][1], acc[i][j], 0, 0, 0);
      }
    __builtin_amdgcn_s_setprio(0); SB();
    if (tt < NT - 2) wait_vmcnt<8>();
    else             wait_vmcnt<0>();
    __builtin_amdgcn_s_barrier(); SB();
  };

  for (int t = 0; t < NT; t += 2) {
    TILE(ic<0>{}, t);
    TILE(ic<1>{}, t + 1);
    pSA += 128; pSB += 128;
  }

  // ---- epilogue ----
#pragma unroll
  for (int f = 0; f < 4; ++f) {
    const int r0 = bm + wm * 64 + f * 16 + (lane >> 4) * 4;
#pragma unroll
    for (int g = 0; g < 4; ++g) {
      const int c = bn + wn * 64 + g * 16 + (lane & 15);
      float bv = 0.f;
      if (MODE == 3 || MODE == 4) bv = bias[c];
#pragma unroll
      for (int r = 0; r < 4; ++r) {
        const size_t idx = (size_t)(r0 + r) * N + c;
        float v = acc[f][g][r];
        if (MODE == 1 || MODE == 2) v += res[idx];
        if (MODE == 3) v = gelu_f(v + bv);
        if (MODE == 4) v += bv + res[idx];
        if (MODE == 0 || MODE == 1 || MODE == 3) outB[idx] = (bf16)v;
        else outF[idx] = v;
      }
    }
  }
}

// ------- fused Performer chunk-sums + segment scan (block = 1 segment) -------
__global__ __launch_bounds__(512) void perf_cs(
    const bf16* __restrict__ kmat, const bf16* __restrict__ vmat, int ld,
    const float* __restrict__ omega, float* __restrict__ CS,
    float* __restrict__ segtot) {
  const int tid = threadIdx.x;
  const int bh = blockIdx.y, b = bh >> 4, h = bh & 15;
  const int seg = blockIdx.x;
  const int s0 = seg * 512;
  __shared__ __align__(16) bf16 vs[512][64];   // XOR-swizzled, 64 KB
  __shared__ float kps[512][8];                // 16 KB
  __shared__ float oms[448];

  {
    const bf16* vb = vmat + ((size_t)(b * Sq + s0)) * ld + h * 64;
#pragma unroll
    for (int p = 0; p < 8; ++p) {
      const int row = p * 64 + (tid >> 3), c16 = (tid & 7) * 8;
      *(uint4*)&vs[row][c16 ^ ((row & 7) * 8)] =
          *(const uint4*)&vb[(size_t)row * ld + c16];
    }
  }
  if (tid < 448) oms[tid] = omega[tid];
  __syncthreads();

  {
    const int row = tid;
    const bf16* kr = kmat + ((size_t)(b * Sq + s0 + row)) * ld + h * 64;
    bf16x8 kv[8];
#pragma unroll
    for (int q = 0; q < 8; ++q) kv[q] = *(const bf16x8*)&kr[q * 8];
    float f[NB];
#pragma unroll
    for (int n = 0; n < NB; ++n) f[n] = 0.f;
#pragma unroll
    for (int d = 0; d < 64; ++d) {
      const float kd = (float)kv[d >> 3][d & 7];
#pragma unroll
      for (int n = 0; n < NB; ++n) f[n] += kd * oms[n * 64 + d];
    }
    float sum = 1e-6f, e[NB];
#pragma unroll
    for (int n = 0; n < NB; ++n) { e[n] = __expf(-0.5f * f[n] * f[n]); sum += e[n]; }
    const float inv = 1.f / sum;
#pragma unroll
    for (int n = 0; n < NB; ++n) kps[row][n] = e[n] * inv;
    kps[row][7] = 0.f;
  }
  __syncthreads();

  if (tid < CSW) {
    const int comp = tid;
    float* outb = CS + ((size_t)bh * NCH + seg * 128) * CSW;
    float r = 0.f;
    if (comp < 8) {
      for (int c = 0; c < 128; ++c) {
        if (comp < 7)
          r += kps[4*c][comp] + kps[4*c+1][comp] + kps[4*c+2][comp] + kps[4*c+3][comp];
        outb[(size_t)c * CSW + comp] = r;
      }
    } else if (comp < 456) {
      const int n = (comp - 8) >> 6, d = (comp - 8) & 63;
      for (int c = 0; c < 128; ++c) {
#pragma unroll
        for (int i = 0; i < 4; ++i) {
          const int row = 4 * c + i;
          r += kps[row][n] * (float)vs[row][d ^ ((row & 7) * 8)];
        }
        outb[(size_t)c * CSW + comp] = r;
      }
    } else {
      for (int c = 0; c < 128; ++c) outb[(size_t)c * CSW + comp] = 0.f;
    }
    segtot[((size_t)bh * 8 + seg) * CSW + comp] = r;
  }
}

// ---------------- exclusive scan of the 8 segment totals ----------------
__global__ __launch_bounds__(256) void perf_scan2(float* __restrict__ segtot) {
  const int bh = blockIdx.x;
  const int c0 = threadIdx.x;
  float run0 = 0.f, run1 = 0.f;
#pragma unroll
  for (int s = 0; s < 8; ++s) {
    float* st = segtot + ((size_t)bh * 8 + s) * CSW;
    float t0 = st[c0]; st[c0] = run0; run0 += t0;
    if (c0 + 256 < CSW) { float t1 = st[c0 + 256]; st[c0 + 256] = run1; run1 += t1; }
  }
}

// ---------------- Performer output ----------------
__global__ __launch_bounds__(256) void perf_out(
    const bf16* __restrict__ qmat, int ldq, const float* __restrict__ omega,
    const float* __restrict__ CS, const float* __restrict__ segtot,
    bf16* __restrict__ attn) {
  const int tid = threadIdx.x;
  const int bh = blockIdx.y, b = bh >> 4, h = bh & 15;
  const int s0 = blockIdx.x * 128;
  const int cg0 = s0 >> 2;
  const int seg = cg0 >> 7;
  __shared__ __align__(16) float Ps[32 * CSW];
  __shared__ float qps[128][8];
  __shared__ float oms[NB * 64];

  {
    const float* src = CS + ((size_t)bh * NCH + cg0) * CSW;
    const float* off = segtot + ((size_t)bh * 8 + seg) * CSW;
    for (int i = tid; i < 32 * CSW / 4; i += 256) {
      f32x4 a = *(const f32x4*)&src[i * 4];
      f32x4 o = *(const f32x4*)&off[(i % (CSW / 4)) * 4];
      a += o;
      *(f32x4*)&Ps[i * 4] = a;
    }
  }
  if (tid < 224) { oms[tid] = omega[tid]; oms[tid + 224] = omega[tid + 224]; }
  __syncthreads();
  {
    const int p = tid >> 1, half = tid & 1;
    const bf16* qr = qmat + ((size_t)(b * Sq + s0 + p)) * ldq + h * 64 + half * 32;
    bf16x8 qv[4];
#pragma unroll
    for (int q = 0; q < 4; ++q) qv[q] = *(const bf16x8*)&qr[q * 8];
    float f[NB];
#pragma unroll
    for (int n = 0; n < NB; ++n) f[n] = 0.f;
#pragma unroll
    for (int d = 0; d < 32; ++d) {
      float qd = (float)qv[d >> 3][d & 7];
#pragma unroll
      for (int n = 0; n < NB; ++n) f[n] += qd * oms[n * 64 + half * 32 + d];
    }
    float sum = 1e-6f;
    float e[NB];
#pragma unroll
    for (int n = 0; n < NB; ++n) {
      float full = f[n] + __shfl_xor(f[n], 1);
      e[n] = __expf(-0.5f * full * full);
      sum += e[n];
    }
    float inv = 1.f / sum;
    if (half == 0) {
      float den = 1e-6f;
      const float* Pr = &Ps[(p >> 2) * CSW];
#pragma unroll
      for (int n = 0; n < NB; ++n) {
        float qn = e[n] * inv;
        qps[p][n] = qn;
        den += qn * Pr[n];
      }
      qps[p][7] = 1.f / den;
    }
  }
  __syncthreads();
  {
    const int d = tid & 63, w = tid >> 6;
    for (int qq = w; qq < 128; qq += 4) {
      const float* Pr = &Ps[(qq >> 2) * CSW + 8 + d];
      float num = 0.f;
#pragma unroll
      for (int n = 0; n < NB; ++n) num += qps[qq][n] * Pr[n * 64];
      attn[((size_t)(b * Sq + s0 + qq)) * Dm + h * 64 + d] = (bf16)(num * qps[qq][7]);
    }
  }
}

// ---------------------------------------------------------------------------
extern "C" void kernel_launch(void* const* d_in, const int* in_sizes, int n_in,
                              void* d_out, int out_size, void* d_ws, size_t ws_size,
                              hipStream_t stream) {
  const float* x    = (const float*)d_in[0];
  const float* lto  = (const float*)d_in[1];
  const float* w_s[4] = {(const float*)d_in[2], (const float*)d_in[3],
                         (const float*)d_in[4], (const float*)d_in[5]};
  const float* w_c[4] = {(const float*)d_in[6], (const float*)d_in[7],
                         (const float*)d_in[8], (const float*)d_in[9]};
  const float* omega_s = (const float*)d_in[10];
  const float* omega_c = (const float*)d_in[11];
  const float* w1 = (const float*)d_in[12];
  const float* b1 = (const float*)d_in[13];
  const float* w2 = (const float*)d_in[14];
  const float* b2 = (const float*)d_in[15];
  const float* ln_a[3] = {(const float*)d_in[16], (const float*)d_in[18], (const float*)d_in[20]};
  const float* ln_b[3] = {(const float*)d_in[17], (const float*)d_in[19], (const float*)d_in[21]};

  char* ws = (char*)d_ws;
  size_t off = 0;
  auto alloc = [&](size_t bytes) -> char* {
    char* p = ws + off;
    off += (bytes + 255) & ~(size_t)255;
    return p;
  };

  const size_t actB = (size_t)Mrows * Dm * sizeof(bf16);     // 16 MiB
  const size_t MB32 = (size_t)Mrows * 2048 * sizeof(bf16);   // 32 MiB

  bf16* wqkv = (bf16*)alloc((size_t)3072 * 1024 * 2);
  bf16* wo_sb = (bf16*)alloc((size_t)1024 * 1024 * 2);
  bf16* wq_cb = (bf16*)alloc((size_t)1024 * 1024 * 2);
  bf16* wkv  = (bf16*)alloc((size_t)2048 * 1024 * 2);
  bf16* wo_cb = (bf16*)alloc((size_t)1024 * 1024 * 2);
  bf16* w1b = (bf16*)alloc((size_t)Dff * Dm * 2);
  bf16* w2b = (bf16*)alloc((size_t)Dff * Dm * 2);
  bf16* xnb  = (bf16*)alloc(actB);
  char* pool = alloc((size_t)Mrows * Dff * 2);               // 64 MiB shared pool
  bf16* qkvb = (bf16*)pool;                                  // 48 MiB (phase 1)
  bf16* kvb  = (bf16*)pool;                                  // 32 MiB (phase 2)
  bf16* qb   = (bf16*)(pool + MB32);                         // 16 MiB (phase 2)
  bf16* hb   = (bf16*)pool;                                  // 64 MiB (phase 3)
  bf16* attnb= (bf16*)alloc(actB);
  bf16* x2b  = (bf16*)alloc(actB);
  bf16* ln1b = (bf16*)alloc(actB);
  float* lto2 = (float*)alloc((size_t)Mrows * Dm * 4);
  float* CSb  = (float*)alloc((size_t)32 * NCH * CSW * 4);
  float* stb  = (float*)alloc((size_t)32 * 8 * CSW * 4);
  bf16* fnb = xnb;   // xnb dead after QKV_s GEMM

  // ---- batched weight conversion ----
  {
    CvtA a;
    const float* srcs[10] = {w_s[0], w_s[1], w_s[2], w_s[3], w_c[0],
                             w_c[1], w_c[2], w_c[3], w1, w2};
    bf16* dsts[10] = {wqkv, wqkv + 1048576, wqkv + 2097152, wo_sb, wq_cb,
                      wkv, wkv + 1048576, wo_cb, w1b, w2b};
    const int SM = 262144, LG = 1048576;
    int st = 0;
    for (int i = 0; i < 10; ++i) {
      a.s[i] = srcs[i]; a.d[i] = dsts[i]; a.start[i] = st;
      st += (i < 8) ? SM : LG;
    }
    a.start[10] = st;
    cvt10<<<st / 256, 256, 0, stream>>>(a);
  }

  dim3 gperf(Sq / 128, Bq * 16);
  dim3 gseg(8, Bq * 16);
  const int gQKV = (Mrows / 128) * (3072 / 128);   // 1536
  const int gKV  = (Mrows / 128) * (2048 / 128);   // 1024
  const int gFF1 = (Mrows / 128) * (4096 / 128);   // 2048
  const int gN1k = (Mrows / 128) * (1024 / 128);   // 512

  // --- self performer on x ---
  ln_kernel<<<Mrows, 256, 0, stream>>>(x, ln_a[0], ln_b[0], xnb);
  gemm128<0><<<gQKV, 256, 0, stream>>>(xnb, wqkv, Mrows, 3072, 1024, nullptr, nullptr, nullptr, qkvb);
  perf_cs<<<gseg, 512, 0, stream>>>(qkvb + 1024, qkvb + 2048, 3072, omega_s, CSb, stb);
  perf_scan2<<<32, 256, 0, stream>>>(stb);
  perf_out<<<gperf, 256, 0, stream>>>(qkvb, 3072, omega_s, CSb, stb, attnb);
  gemm128<1><<<gN1k, 256, 0, stream>>>(attnb, wo_sb, Mrows, 1024, 1024, nullptr, x, nullptr, x2b);

  // --- cross performer: q from LN(lto), k/v from updated x ---
  ln_kernel<<<Mrows, 256, 0, stream>>>(lto, ln_a[1], ln_b[1], ln1b);
  gemm128<0><<<gN1k, 256, 0, stream>>>(ln1b, wq_cb, Mrows, 1024, 1024, nullptr, nullptr, nullptr, qb);
  gemm128<0><<<gKV, 256, 0, stream>>>(x2b, wkv, Mrows, 2048, 1024, nullptr, nullptr, nullptr, kvb);
  perf_cs<<<gseg, 512, 0, stream>>>(kvb, kvb + 1024, 2048, omega_c, CSb, stb);
  perf_scan2<<<32, 256, 0, stream>>>(stb);
  perf_out<<<gperf, 256, 0, stream>>>(qb, 1024, omega_c, CSb, stb, attnb);
  gemm128<2><<<gN1k, 256, 0, stream>>>(attnb, wo_cb, Mrows, 1024, 1024, nullptr, lto, lto2, nullptr);

  // --- FFN ---
  ln_kernel<<<Mrows, 256, 0, stream>>>(lto2, ln_a[2], ln_b[2], fnb);
  gemm128<3><<<gFF1, 256, 0, stream>>>(fnb, w1b, Mrows, 4096, 1024, b1, nullptr, nullptr, hb);
  gemm128<4><<<gN1k, 256, 0, stream>>>(hb, w2b, Mrows, 1024, 4096, b2, lto2, (float*)d_out, nullptr);
}

// Round 9
// 511.119 us; speedup vs baseline: 1.6176x; 1.0209x over previous
//
#include <hip/hip_runtime.h>
#include <cstdint>
#include <cstddef>

typedef __bf16 bf16;
typedef __bf16 bf16x8 __attribute__((ext_vector_type(8)));
typedef __bf16 bf16x4 __attribute__((ext_vector_type(4)));
typedef float  f32x4  __attribute__((ext_vector_type(4)));

#define NB 7
static constexpr int Bq = 2, Sq = 4096, Dm = 1024, Dff = 4096;
static constexpr int Mrows = Bq * Sq;     // 8192
static constexpr int NCH = Sq / 4;        // 1024 chunks per (b,h)
static constexpr int CSW = 464;           // padded prefix-state row width

template <int V> struct ic { static constexpr int value = V; };

__device__ __forceinline__ void gload16(const void* g, void* l) {
  __builtin_amdgcn_global_load_lds((__attribute__((address_space(1))) void*)g,
                                   (__attribute__((address_space(3))) void*)l,
                                   16, 0, 0);
}

template <int N> __device__ __forceinline__ void wait_vmcnt() {
  asm volatile("s_waitcnt vmcnt(%0)" :: "n"(N) : "memory");
}
__device__ __forceinline__ void wait_lgkm0() {
  asm volatile("s_waitcnt lgkmcnt(0)" ::: "memory");
}
__device__ __forceinline__ void SB() { __builtin_amdgcn_sched_barrier(0); }

__device__ __forceinline__ float gelu_f(float x) {
  const float c = 0.79788456080286535588f;
  float z = c * (x + 0.044715f * x * x * x);
  float t = 1.f - 2.f / (__expf(2.f * z) + 1.f);   // tanh(z)
  return 0.5f * x * (1.f + t);
}

// ---------------- batched f32 -> bf16 convert (10 regions, 1 launch) ----------
struct CvtA {
  const float* s[10];
  bf16* d[10];
  int start[11];
};
__global__ __launch_bounds__(256) void cvt10(CvtA a) {
  const int i = blockIdx.x * 256 + threadIdx.x;
  int r = 0;
#pragma unroll
  for (int k = 1; k < 10; ++k) r += (i >= a.start[k]);
  const int o = i - a.start[r];
  f32x4 v = *(const f32x4*)&a.s[r][(size_t)o * 4];
  bf16x4 ov;
#pragma unroll
  for (int e = 0; e < 4; ++e) ov[e] = (bf16)v[e];
  *(bf16x4*)&a.d[r][(size_t)o * 4] = ov;
}

// ---------------- LayerNorm (ddof=1, /(std+eps)) -> bf16 ----------------
__global__ __launch_bounds__(256) void ln_kernel(const float* __restrict__ x,
                                                 const float* __restrict__ alpha,
                                                 const float* __restrict__ beta,
                                                 bf16* __restrict__ out) {
  const int row = blockIdx.x, tid = threadIdx.x;
  const float* xr = x + (size_t)row * Dm;
  f32x4 v = *(const f32x4*)&xr[tid * 4];
  float s  = v[0] + v[1] + v[2] + v[3];
  float s2 = v[0]*v[0] + v[1]*v[1] + v[2]*v[2] + v[3]*v[3];
#pragma unroll
  for (int o = 32; o > 0; o >>= 1) { s += __shfl_xor(s, o); s2 += __shfl_xor(s2, o); }
  __shared__ float red[8];
  const int wid = tid >> 6, lane = tid & 63;
  if (lane == 0) { red[wid] = s; red[wid + 4] = s2; }
  __syncthreads();
  s  = red[0] + red[1] + red[2] + red[3];
  s2 = red[4] + red[5] + red[6] + red[7];
  const float mean = s * (1.f / 1024.f);
  float var = (s2 - s * mean) * (1.f / 1023.f);
  var = fmaxf(var, 0.f);
  const float inv = 1.f / (sqrtf(var) + 1e-6f);
  f32x4 a4 = *(const f32x4*)&alpha[tid * 4];
  f32x4 b4 = *(const f32x4*)&beta[tid * 4];
  bf16x4 o4;
#pragma unroll
  for (int e = 0; e < 4; ++e) o4[e] = (bf16)(a4[e] * (v[e] - mean) * inv + b4[e]);
  *(bf16x4*)&out[(size_t)row * Dm + tid * 4] = o4;
}

// ------------- 128x128 double-buffered GEMM, 256 threads, 2 blocks/CU -------------
// r8 schedule + SUPERTILE block mapping: 8x8-block supertiles (64 blocks = one
// XCD's residency); XCD-contiguous linearization gives each XCD a row-stripe of
// supertiles swept column-wise -> per-K-slice L2 working set ~256 KB, B fetched
// once per XCD. Requires nr%8==0, nc%8==0, nwg%8==0 (all GEMMs here qualify).
// MODE 0: out bf16 | 1: +res(f32)->bf16 | 2: +res(f32)->f32 | 3: +bias,gelu->bf16
// MODE 4: +bias+res(f32)->f32
template <int MODE>
__global__ __launch_bounds__(256, 2) void gemm128(
    const bf16* __restrict__ A, const bf16* __restrict__ Bw,
    int M, int N, int K,
    const float* __restrict__ bias, const float* __restrict__ res,
    float* __restrict__ outF, bf16* __restrict__ outB) {
  __shared__ __align__(16) char lds[65536];

  const int tid = threadIdx.x;
  const int lane = tid & 63, wid = tid >> 6;
  const int wm = wid >> 1, wn = wid & 1;

  // ---- supertile mapping ----
  const int nwg = gridDim.x;
  const int nc = N >> 7;                 // block-columns
  const int nsc = nc >> 3;               // supertile-columns
  const int lin = (blockIdx.x & 7) * (nwg >> 3) + (blockIdx.x >> 3); // XCD-contig
  const int s = lin >> 6, w = lin & 63;
  const int sr = s / nsc, sc = s - sr * nsc;
  const int bm = (sr * 8 + (w >> 3)) * 128;
  const int bn = (sc * 8 + (w & 7)) * 128;
  const int NT = K >> 6;                 // always even (K = 1024/2048/4096)

  // ---- staging: global sources (pre-swizzled k offset), LDS dests ----
  const int srow = tid >> 3;                       // 0..31
  const int scol = ((tid & 7) ^ (srow & 7)) * 8;   // inverse-swizzled k offset
  const bf16* pSA = A  + (size_t)(bm + srow) * K + scol;   // tile 0 source
  const bf16* pSB = Bw + (size_t)(bn + srow) * K + scol;
  const size_t cK = (size_t)32 * K;                // row-chunk stride (elements)
  const int stDa = wid * 1024;                     // LDS dest base (wave-uniform)

  auto stage = [&](int buf, const bf16* sa, const bf16* sb) {
#pragma unroll
    for (int c = 0; c < 4; ++c) {
      gload16(sa + (size_t)c * cK, &lds[buf * 16384 + c * 4096 + stDa]);
      gload16(sb + (size_t)c * cK, &lds[32768 + buf * 16384 + c * 4096 + stDa]);
    }
  };

  // ---- LDS read base offsets (per-lane, loop-invariant) ----
  const int lr = lane & 15, uo = lane >> 4;
  const int rdA0 = (wm * 64 + lr) * 128 + ((uo)     ^ (lr & 7)) * 16;   // kh=0
  const int rdA1 = (wm * 64 + lr) * 128 + ((4 + uo) ^ (lr & 7)) * 16;   // kh=1
  const int rdB0 = 32768 + (wn * 64 + lr) * 128 + ((uo)     ^ (lr & 7)) * 16;
  const int rdB1 = 32768 + (wn * 64 + lr) * 128 + ((4 + uo) ^ (lr & 7)) * 16;

  f32x4 acc[4][4] = {};
  bf16x8 a[4][2], b[4][2];

  // prologue: stage tiles 0 and 1
  stage(0, pSA, pSB);
  stage(1, pSA + 64, pSB + 64);
  pSA += 128; pSB += 128;            // now points at tile-2 source
  wait_vmcnt<8>();                   // tile 0 fully in LDS
  __builtin_amdgcn_s_barrier();

  // one K-tile: reads (const offsets) -> lgkm0 -> barrier -> stage(t+2) ->
  // 32 MFMA -> vmcnt(8)/(0) -> barrier
  auto TILE = [&](auto BUFC, int tt) {
    constexpr int BUF = decltype(BUFC)::value;
#pragma unroll
    for (int i = 0; i < 4; ++i) {
      a[i][0] = *(const bf16x8*)&lds[rdA0 + BUF * 16384 + i * 2048];
      a[i][1] = *(const bf16x8*)&lds[rdA1 + BUF * 16384 + i * 2048];
    }
#pragma unroll
    for (int j = 0; j < 4; ++j) {
      b[j][0] = *(const bf16x8*)&lds[rdB0 + BUF * 16384 + j * 2048];
      b[j][1] = *(const bf16x8*)&lds[rdB1 + BUF * 16384 + j * 2048];
    }
    wait_lgkm0(); SB();
    __builtin_amdgcn_s_barrier(); SB();

    if (tt + 2 < NT) stage(BUF, pSA + (size_t)(tt & 1) * 64,
                                pSB + (size_t)(tt & 1) * 64);
    SB();
    __builtin_amdgcn_s_setprio(1);
#pragma unroll
    for (int i = 0; i < 4; ++i)
#pragma unroll
      for (int j = 0; j < 4; ++j) {
        acc[i][j] = __builtin_amdgcn_mfma_f32_16x16x32_bf16(a[i][0], b[j][0], acc[i][j], 0, 0, 0);
        acc[i][j] = __builtin_amdgcn_mfma_f32_16x16x32_bf16(a[i][1], b[j][1], acc[i][j], 0, 0, 0);
      }
    __builtin_amdgcn_s_setprio(0); SB();
    if (tt < NT - 2) wait_vmcnt<8>();
    else             wait_vmcnt<0>();
    __builtin_amdgcn_s_barrier(); SB();
  };

  for (int t = 0; t < NT; t += 2) {
    TILE(ic<0>{}, t);
    TILE(ic<1>{}, t + 1);
    pSA += 128; pSB += 128;
  }

  // ---- epilogue ----
#pragma unroll
  for (int f = 0; f < 4; ++f) {
    const int r0 = bm + wm * 64 + f * 16 + (lane >> 4) * 4;
#pragma unroll
    for (int g = 0; g < 4; ++g) {
      const int c = bn + wn * 64 + g * 16 + (lane & 15);
      float bv = 0.f;
      if (MODE == 3 || MODE == 4) bv = bias[c];
#pragma unroll
      for (int r = 0; r < 4; ++r) {
        const size_t idx = (size_t)(r0 + r) * N + c;
        float v = acc[f][g][r];
        if (MODE == 1 || MODE == 2) v += res[idx];
        if (MODE == 3) v = gelu_f(v + bv);
        if (MODE == 4) v += bv + res[idx];
        if (MODE == 0 || MODE == 1 || MODE == 3) outB[idx] = (bf16)v;
        else outF[idx] = v;
      }
    }
  }
}

// ------- fused Performer chunk-sums + segment scan (block = 1 segment) -------
__global__ __launch_bounds__(512) void perf_cs(
    const bf16* __restrict__ kmat, const bf16* __restrict__ vmat, int ld,
    const float* __restrict__ omega, float* __restrict__ CS,
    float* __restrict__ segtot) {
  const int tid = threadIdx.x;
  const int bh = blockIdx.y, b = bh >> 4, h = bh & 15;
  const int seg = blockIdx.x;
  const int s0 = seg * 512;
  __shared__ __align__(16) bf16 vs[512][64];   // XOR-swizzled, 64 KB
  __shared__ float kps[512][8];                // 16 KB
  __shared__ float oms[448];

  {
    const bf16* vb = vmat + ((size_t)(b * Sq + s0)) * ld + h * 64;
#pragma unroll
    for (int p = 0; p < 8; ++p) {
      const int row = p * 64 + (tid >> 3), c16 = (tid & 7) * 8;
      *(uint4*)&vs[row][c16 ^ ((row & 7) * 8)] =
          *(const uint4*)&vb[(size_t)row * ld + c16];
    }
  }
  if (tid < 448) oms[tid] = omega[tid];
  __syncthreads();

  {
    const int row = tid;
    const bf16* kr = kmat + ((size_t)(b * Sq + s0 + row)) * ld + h * 64;
    bf16x8 kv[8];
#pragma unroll
    for (int q = 0; q < 8; ++q) kv[q] = *(const bf16x8*)&kr[q * 8];
    float f[NB];
#pragma unroll
    for (int n = 0; n < NB; ++n) f[n] = 0.f;
#pragma unroll
    for (int d = 0; d < 64; ++d) {
      const float kd = (float)kv[d >> 3][d & 7];
#pragma unroll
      for (int n = 0; n < NB; ++n) f[n] += kd * oms[n * 64 + d];
    }
    float sum = 1e-6f, e[NB];
#pragma unroll
    for (int n = 0; n < NB; ++n) { e[n] = __expf(-0.5f * f[n] * f[n]); sum += e[n]; }
    const float inv = 1.f / sum;
#pragma unroll
    for (int n = 0; n < NB; ++n) kps[row][n] = e[n] * inv;
    kps[row][7] = 0.f;
  }
  __syncthreads();

  if (tid < CSW) {
    const int comp = tid;
    float* outb = CS + ((size_t)bh * NCH + seg * 128) * CSW;
    float r = 0.f;
    if (comp < 8) {
      for (int c = 0; c < 128; ++c) {
        if (comp < 7)
          r += kps[4*c][comp] + kps[4*c+1][comp] + kps[4*c+2][comp] + kps[4*c+3][comp];
        outb[(size_t)c * CSW + comp] = r;
      }
    } else if (comp < 456) {
      const int n = (comp - 8) >> 6, d = (comp - 8) & 63;
      for (int c = 0; c < 128; ++c) {
#pragma unroll
        for (int i = 0; i < 4; ++i) {
          const int row = 4 * c + i;
          r += kps[row][n] * (float)vs[row][d ^ ((row & 7) * 8)];
        }
        outb[(size_t)c * CSW + comp] = r;
      }
    } else {
      for (int c = 0; c < 128; ++c) outb[(size_t)c * CSW + comp] = 0.f;
    }
    segtot[((size_t)bh * 8 + seg) * CSW + comp] = r;
  }
}

// ---------------- exclusive scan of the 8 segment totals ----------------
__global__ __launch_bounds__(256) void perf_scan2(float* __restrict__ segtot) {
  const int bh = blockIdx.x;
  const int c0 = threadIdx.x;
  float run0 = 0.f, run1 = 0.f;
#pragma unroll
  for (int s = 0; s < 8; ++s) {
    float* st = segtot + ((size_t)bh * 8 + s) * CSW;
    float t0 = st[c0]; st[c0] = run0; run0 += t0;
    if (c0 + 256 < CSW) { float t1 = st[c0 + 256]; st[c0 + 256] = run1; run1 += t1; }
  }
}

// ---------------- Performer output ----------------
__global__ __launch_bounds__(256) void perf_out(
    const bf16* __restrict__ qmat, int ldq, const float* __restrict__ omega,
    const float* __restrict__ CS, const float* __restrict__ segtot,
    bf16* __restrict__ attn) {
  const int tid = threadIdx.x;
  const int bh = blockIdx.y, b = bh >> 4, h = bh & 15;
  const int s0 = blockIdx.x * 128;
  const int cg0 = s0 >> 2;
  const int seg = cg0 >> 7;
  __shared__ __align__(16) float Ps[32 * CSW];
  __shared__ float qps[128][8];
  __shared__ float oms[NB * 64];

  {
    const float* src = CS + ((size_t)bh * NCH + cg0) * CSW;
    const float* off = segtot + ((size_t)bh * 8 + seg) * CSW;
    for (int i = tid; i < 32 * CSW / 4; i += 256) {
      f32x4 a = *(const f32x4*)&src[i * 4];
      f32x4 o = *(const f32x4*)&off[(i % (CSW / 4)) * 4];
      a += o;
      *(f32x4*)&Ps[i * 4] = a;
    }
  }
  if (tid < 224) { oms[tid] = omega[tid]; oms[tid + 224] = omega[tid + 224]; }
  __syncthreads();
  {
    const int p = tid >> 1, half = tid & 1;
    const bf16* qr = qmat + ((size_t)(b * Sq + s0 + p)) * ldq + h * 64 + half * 32;
    bf16x8 qv[4];
#pragma unroll
    for (int q = 0; q < 4; ++q) qv[q] = *(const bf16x8*)&qr[q * 8];
    float f[NB];
#pragma unroll
    for (int n = 0; n < NB; ++n) f[n] = 0.f;
#pragma unroll
    for (int d = 0; d < 32; ++d) {
      float qd = (float)qv[d >> 3][d & 7];
#pragma unroll
      for (int n = 0; n < NB; ++n) f[n] += qd * oms[n * 64 + half * 32 + d];
    }
    float sum = 1e-6f;
    float e[NB];
#pragma unroll
    for (int n = 0; n < NB; ++n) {
      float full = f[n] + __shfl_xor(f[n], 1);
      e[n] = __expf(-0.5f * full * full);
      sum += e[n];
    }
    float inv = 1.f / sum;
    if (half == 0) {
      float den = 1e-6f;
      const float* Pr = &Ps[(p >> 2) * CSW];
#pragma unroll
      for (int n = 0; n < NB; ++n) {
        float qn = e[n] * inv;
        qps[p][n] = qn;
        den += qn * Pr[n];
      }
      qps[p][7] = 1.f / den;
    }
  }
  __syncthreads();
  {
    const int d = tid & 63, w = tid >> 6;
    for (int qq = w; qq < 128; qq += 4) {
      const float* Pr = &Ps[(qq >> 2) * CSW + 8 + d];
      float num = 0.f;
#pragma unroll
      for (int n = 0; n < NB; ++n) num += qps[qq][n] * Pr[n * 64];
      attn[((size_t)(b * Sq + s0 + qq)) * Dm + h * 64 + d] = (bf16)(num * qps[qq][7]);
    }
  }
}

// ---------------------------------------------------------------------------
extern "C" void kernel_launch(void* const* d_in, const int* in_sizes, int n_in,
                              void* d_out, int out_size, void* d_ws, size_t ws_size,
                              hipStream_t stream) {
  const float* x    = (const float*)d_in[0];
  const float* lto  = (const float*)d_in[1];
  const float* w_s[4] = {(const float*)d_in[2], (const float*)d_in[3],
                         (const float*)d_in[4], (const float*)d_in[5]};
  const float* w_c[4] = {(const float*)d_in[6], (const float*)d_in[7],
                         (const float*)d_in[8], (const float*)d_in[9]};
  const float* omega_s = (const float*)d_in[10];
  const float* omega_c = (const float*)d_in[11];
  const float* w1 = (const float*)d_in[12];
  const float* b1 = (const float*)d_in[13];
  const float* w2 = (const float*)d_in[14];
  const float* b2 = (const float*)d_in[15];
  const float* ln_a[3] = {(const float*)d_in[16], (const float*)d_in[18], (const float*)d_in[20]};
  const float* ln_b[3] = {(const float*)d_in[17], (const float*)d_in[19], (const float*)d_in[21]};

  char* ws = (char*)d_ws;
  size_t off = 0;
  auto alloc = [&](size_t bytes) -> char* {
    char* p = ws + off;
    off += (bytes + 255) & ~(size_t)255;
    return p;
  };

  const size_t actB = (size_t)Mrows * Dm * sizeof(bf16);     // 16 MiB
  const size_t MB32 = (size_t)Mrows * 2048 * sizeof(bf16);   // 32 MiB

  bf16* wqkv = (bf16*)alloc((size_t)3072 * 1024 * 2);
  bf16* wo_sb = (bf16*)alloc((size_t)1024 * 1024 * 2);
  bf16* wq_cb = (bf16*)alloc((size_t)1024 * 1024 * 2);
  bf16* wkv  = (bf16*)alloc((size_t)2048 * 1024 * 2);
  bf16* wo_cb = (bf16*)alloc((size_t)1024 * 1024 * 2);
  bf16* w1b = (bf16*)alloc((size_t)Dff * Dm * 2);
  bf16* w2b = (bf16*)alloc((size_t)Dff * Dm * 2);
  bf16* xnb  = (bf16*)alloc(actB);
  char* pool = alloc((size_t)Mrows * Dff * 2);               // 64 MiB shared pool
  bf16* qkvb = (bf16*)pool;                                  // 48 MiB (phase 1)
  bf16* kvb  = (bf16*)pool;                                  // 32 MiB (phase 2)
  bf16* qb   = (bf16*)(pool + MB32);                         // 16 MiB (phase 2)
  bf16* hb   = (bf16*)pool;                                  // 64 MiB (phase 3)
  bf16* attnb= (bf16*)alloc(actB);
  bf16* x2b  = (bf16*)alloc(actB);
  bf16* ln1b = (bf16*)alloc(actB);
  float* lto2 = (float*)alloc((size_t)Mrows * Dm * 4);
  float* CSb  = (float*)alloc((size_t)32 * NCH * CSW * 4);
  float* stb  = (float*)alloc((size_t)32 * 8 * CSW * 4);
  bf16* fnb = xnb;   // xnb dead after QKV_s GEMM

  // ---- batched weight conversion ----
  {
    CvtA a;
    const float* srcs[10] = {w_s[0], w_s[1], w_s[2], w_s[3], w_c[0],
                             w_c[1], w_c[2], w_c[3], w1, w2};
    bf16* dsts[10] = {wqkv, wqkv + 1048576, wqkv + 2097152, wo_sb, wq_cb,
                      wkv, wkv + 1048576, wo_cb, w1b, w2b};
    const int SM = 262144, LG = 1048576;
    int st = 0;
    for (int i = 0; i < 10; ++i) {
      a.s[i] = srcs[i]; a.d[i] = dsts[i]; a.start[i] = st;
      st += (i < 8) ? SM : LG;
    }
    a.start[10] = st;
    cvt10<<<st / 256, 256, 0, stream>>>(a);
  }

  dim3 gperf(Sq / 128, Bq * 16);
  dim3 gseg(8, Bq * 16);
  const int gQKV = (Mrows / 128) * (3072 / 128);   // 1536
  const int gKV  = (Mrows / 128) * (2048 / 128);   // 1024
  const int gFF1 = (Mrows / 128) * (4096 / 128);   // 2048
  const int gN1k = (Mrows / 128) * (1024 / 128);   // 512

  // --- self performer on x ---
  ln_kernel<<<Mrows, 256, 0, stream>>>(x, ln_a[0], ln_b[0], xnb);
  gemm128<0><<<gQKV, 256, 0, stream>>>(xnb, wqkv, Mrows, 3072, 1024, nullptr, nullptr, nullptr, qkvb);
  perf_cs<<<gseg, 512, 0, stream>>>(qkvb + 1024, qkvb + 2048, 3072, omega_s, CSb, stb);
  perf_scan2<<<32, 256, 0, stream>>>(stb);
  perf_out<<<gperf, 256, 0, stream>>>(qkvb, 3072, omega_s, CSb, stb, attnb);
  gemm128<1><<<gN1k, 256, 0, stream>>>(attnb, wo_sb, Mrows, 1024, 1024, nullptr, x, nullptr, x2b);

  // --- cross performer: q from LN(lto), k/v from updated x ---
  ln_kernel<<<Mrows, 256, 0, stream>>>(lto, ln_a[1], ln_b[1], ln1b);
  gemm128<0><<<gN1k, 256, 0, stream>>>(ln1b, wq_cb, Mrows, 1024, 1024, nullptr, nullptr, nullptr, qb);
  gemm128<0><<<gKV, 256, 0, stream>>>(x2b, wkv, Mrows, 2048, 1024, nullptr, nullptr, nullptr, kvb);
  perf_cs<<<gseg, 512, 0, stream>>>(kvb, kvb + 1024, 2048, omega_c, CSb, stb);
  perf_scan2<<<32, 256, 0, stream>>>(stb);
  perf_out<<<gperf, 256, 0, stream>>>(qb, 1024, omega_c, CSb, stb, attnb);
  gemm128<2><<<gN1k, 256, 0, stream>>>(attnb, wo_cb, Mrows, 1024, 1024, nullptr, lto, lto2, nullptr);

  // --- FFN ---
  ln_kernel<<<Mrows, 256, 0, stream>>>(lto2, ln_a[2], ln_b[2], fnb);
  gemm128<3><<<gFF1, 256, 0, stream>>>(fnb, w1b, Mrows, 4096, 1024, b1, nullptr, nullptr, hb);
  gemm128<4><<<gN1k, 256, 0, stream>>>(hb, w2b, Mrows, 1024, 4096, b2, lto2, (float*)d_out, nullptr);
}

// Round 10
// 499.341 us; speedup vs baseline: 1.6557x; 1.0236x over previous
//
#include <hip/hip_runtime.h>
#include <cstdint>
#include <cstddef>

typedef __bf16 bf16;
typedef __bf16 bf16x8 __attribute__((ext_vector_type(8)));
typedef __bf16 bf16x4 __attribute__((ext_vector_type(4)));
typedef float  f32x4  __attribute__((ext_vector_type(4)));

#define NB 7
static constexpr int Bq = 2, Sq = 4096, Dm = 1024, Dff = 4096;
static constexpr int Mrows = Bq * Sq;     // 8192
static constexpr int NCH = Sq / 4;        // 1024 chunks per (b,h)
static constexpr int CSW = 464;           // padded prefix-state row width

template <int V> struct ic { static constexpr int value = V; };

__device__ __forceinline__ void gload16(const void* g, void* l) {
  __builtin_amdgcn_global_load_lds((__attribute__((address_space(1))) void*)g,
                                   (__attribute__((address_space(3))) void*)l,
                                   16, 0, 0);
}

template <int N> __device__ __forceinline__ void wait_vmcnt() {
  asm volatile("s_waitcnt vmcnt(%0)" :: "n"(N) : "memory");
}
__device__ __forceinline__ void wait_lgkm0() {
  asm volatile("s_waitcnt lgkmcnt(0)" ::: "memory");
}
__device__ __forceinline__ void SB() { __builtin_amdgcn_sched_barrier(0); }

__device__ __forceinline__ float gelu_f(float x) {
  const float c = 0.79788456080286535588f;
  float z = c * (x + 0.044715f * x * x * x);
  float t = 1.f - 2.f / (__expf(2.f * z) + 1.f);   // tanh(z)
  return 0.5f * x * (1.f + t);
}

// ---------------- batched f32 -> bf16 convert (10 regions, 1 launch) ----------
struct CvtA {
  const float* s[10];
  bf16* d[10];
  int start[11];
};
__global__ __launch_bounds__(256) void cvt10(CvtA a) {
  const int i = blockIdx.x * 256 + threadIdx.x;
  int r = 0;
#pragma unroll
  for (int k = 1; k < 10; ++k) r += (i >= a.start[k]);
  const int o = i - a.start[r];
  f32x4 v = *(const f32x4*)&a.s[r][(size_t)o * 4];
  bf16x4 ov;
#pragma unroll
  for (int e = 0; e < 4; ++e) ov[e] = (bf16)v[e];
  *(bf16x4*)&a.d[r][(size_t)o * 4] = ov;
}

// ---------------- LayerNorm (ddof=1, /(std+eps)) -> bf16 ----------------
__global__ __launch_bounds__(256) void ln_kernel(const float* __restrict__ x,
                                                 const float* __restrict__ alpha,
                                                 const float* __restrict__ beta,
                                                 bf16* __restrict__ out) {
  const int row = blockIdx.x, tid = threadIdx.x;
  const float* xr = x + (size_t)row * Dm;
  f32x4 v = *(const f32x4*)&xr[tid * 4];
  float s  = v[0] + v[1] + v[2] + v[3];
  float s2 = v[0]*v[0] + v[1]*v[1] + v[2]*v[2] + v[3]*v[3];
#pragma unroll
  for (int o = 32; o > 0; o >>= 1) { s += __shfl_xor(s, o); s2 += __shfl_xor(s2, o); }
  __shared__ float red[8];
  const int wid = tid >> 6, lane = tid & 63;
  if (lane == 0) { red[wid] = s; red[wid + 4] = s2; }
  __syncthreads();
  s  = red[0] + red[1] + red[2] + red[3];
  s2 = red[4] + red[5] + red[6] + red[7];
  const float mean = s * (1.f / 1024.f);
  float var = (s2 - s * mean) * (1.f / 1023.f);
  var = fmaxf(var, 0.f);
  const float inv = 1.f / (sqrtf(var) + 1e-6f);
  f32x4 a4 = *(const f32x4*)&alpha[tid * 4];
  f32x4 b4 = *(const f32x4*)&beta[tid * 4];
  bf16x4 o4;
#pragma unroll
  for (int e = 0; e < 4; ++e) o4[e] = (bf16)(a4[e] * (v[e] - mean) * inv + b4[e]);
  *(bf16x4*)&out[(size_t)row * Dm + tid * 4] = o4;
}

// ------------- 128x128 double-buffered GEMM, 256 threads, 2 blocks/CU -------------
// r9 + UNPINNED compute region: no sched_barrier / setprio between stage-issue
// and MFMA -> compiler interleaves global_load_lds with MFMA (m141 lesson).
// Correctness fences kept: lgkm0+SB before barrier #1 (reads drained before
// overwrite), SB after barriers, SB before counted vmcnt. Supertile mapping
// (8x8-block = one XCD residency) for L2 locality.
// MODE 0: out bf16 | 1: +res(f32)->bf16 | 2: +res(f32)->f32 | 3: +bias,gelu->bf16
// MODE 4: +bias+res(f32)->f32
template <int MODE>
__global__ __launch_bounds__(256, 2) void gemm128(
    const bf16* __restrict__ A, const bf16* __restrict__ Bw,
    int M, int N, int K,
    const float* __restrict__ bias, const float* __restrict__ res,
    float* __restrict__ outF, bf16* __restrict__ outB) {
  __shared__ __align__(16) char lds[65536];

  const int tid = threadIdx.x;
  const int lane = tid & 63, wid = tid >> 6;
  const int wm = wid >> 1, wn = wid & 1;

  // ---- supertile mapping ----
  const int nwg = gridDim.x;
  const int nc = N >> 7;                 // block-columns
  const int nsc = nc >> 3;               // supertile-columns
  const int lin = (blockIdx.x & 7) * (nwg >> 3) + (blockIdx.x >> 3); // XCD-contig
  const int s = lin >> 6, w = lin & 63;
  const int sr = s / nsc, sc = s - sr * nsc;
  const int bm = (sr * 8 + (w >> 3)) * 128;
  const int bn = (sc * 8 + (w & 7)) * 128;
  const int NT = K >> 6;                 // always even (K = 1024/2048/4096)

  // ---- staging: global sources (pre-swizzled k offset), LDS dests ----
  const int srow = tid >> 3;                       // 0..31
  const int scol = ((tid & 7) ^ (srow & 7)) * 8;   // inverse-swizzled k offset
  const bf16* pSA = A  + (size_t)(bm + srow) * K + scol;   // tile 0 source
  const bf16* pSB = Bw + (size_t)(bn + srow) * K + scol;
  const size_t cK = (size_t)32 * K;                // row-chunk stride (elements)
  const int stDa = wid * 1024;                     // LDS dest base (wave-uniform)

  auto stage = [&](int buf, const bf16* sa, const bf16* sb) {
#pragma unroll
    for (int c = 0; c < 4; ++c) {
      gload16(sa + (size_t)c * cK, &lds[buf * 16384 + c * 4096 + stDa]);
      gload16(sb + (size_t)c * cK, &lds[32768 + buf * 16384 + c * 4096 + stDa]);
    }
  };

  // ---- LDS read base offsets (per-lane, loop-invariant) ----
  const int lr = lane & 15, uo = lane >> 4;
  const int rdA0 = (wm * 64 + lr) * 128 + ((uo)     ^ (lr & 7)) * 16;   // kh=0
  const int rdA1 = (wm * 64 + lr) * 128 + ((4 + uo) ^ (lr & 7)) * 16;   // kh=1
  const int rdB0 = 32768 + (wn * 64 + lr) * 128 + ((uo)     ^ (lr & 7)) * 16;
  const int rdB1 = 32768 + (wn * 64 + lr) * 128 + ((4 + uo) ^ (lr & 7)) * 16;

  f32x4 acc[4][4] = {};
  bf16x8 a[4][2], b[4][2];

  // prologue: stage tiles 0 and 1
  stage(0, pSA, pSB);
  stage(1, pSA + 64, pSB + 64);
  pSA += 128; pSB += 128;            // now points at tile-2 source
  wait_vmcnt<8>();                   // tile 0 fully in LDS
  __builtin_amdgcn_s_barrier();

  // one K-tile: reads (const offsets) -> lgkm0 -> barrier -> {stage(t+2) | 32
  // MFMA, compiler-interleaved} -> vmcnt(8)/(0) -> barrier
  auto TILE = [&](auto BUFC, int tt) {
    constexpr int BUF = decltype(BUFC)::value;
#pragma unroll
    for (int i = 0; i < 4; ++i) {
      a[i][0] = *(const bf16x8*)&lds[rdA0 + BUF * 16384 + i * 2048];
      a[i][1] = *(const bf16x8*)&lds[rdA1 + BUF * 16384 + i * 2048];
    }
#pragma unroll
    for (int j = 0; j < 4; ++j) {
      b[j][0] = *(const bf16x8*)&lds[rdB0 + BUF * 16384 + j * 2048];
      b[j][1] = *(const bf16x8*)&lds[rdB1 + BUF * 16384 + j * 2048];
    }
    wait_lgkm0(); SB();
    __builtin_amdgcn_s_barrier(); SB();

    if (tt + 2 < NT) stage(BUF, pSA + (size_t)(tt & 1) * 64,
                                pSB + (size_t)(tt & 1) * 64);
    // (no sched_barrier, no setprio: compiler interleaves staging with MFMA)
#pragma unroll
    for (int i = 0; i < 4; ++i)
#pragma unroll
      for (int j = 0; j < 4; ++j) {
        acc[i][j] = __builtin_amdgcn_mfma_f32_16x16x32_bf16(a[i][0], b[j][0], acc[i][j], 0, 0, 0);
        acc[i][j] = __builtin_amdgcn_mfma_f32_16x16x32_bf16(a[i][1], b[j][1], acc[i][j], 0, 0, 0);
      }
    SB();
    if (tt < NT - 2) wait_vmcnt<8>();
    else             wait_vmcnt<0>();
    __builtin_amdgcn_s_barrier(); SB();
  };

  for (int t = 0; t < NT; t += 2) {
    TILE(ic<0>{}, t);
    TILE(ic<1>{}, t + 1);
    pSA += 128; pSB += 128;
  }

  // ---- epilogue ----
#pragma unroll
  for (int f = 0; f < 4; ++f) {
    const int r0 = bm + wm * 64 + f * 16 + (lane >> 4) * 4;
#pragma unroll
    for (int g = 0; g < 4; ++g) {
      const int c = bn + wn * 64 + g * 16 + (lane & 15);
      float bv = 0.f;
      if (MODE == 3 || MODE == 4) bv = bias[c];
#pragma unroll
      for (int r = 0; r < 4; ++r) {
        const size_t idx = (size_t)(r0 + r) * N + c;
        float v = acc[f][g][r];
        if (MODE == 1 || MODE == 2) v += res[idx];
        if (MODE == 3) v = gelu_f(v + bv);
        if (MODE == 4) v += bv + res[idx];
        if (MODE == 0 || MODE == 1 || MODE == 3) outB[idx] = (bf16)v;
        else outF[idx] = v;
      }
    }
  }
}

// ------- fused Performer chunk-sums + segment scan (block = 1 segment) -------
// CS stored in bf16 (halves traffic); segtot (raw segment totals) stays f32.
__global__ __launch_bounds__(512) void perf_cs(
    const bf16* __restrict__ kmat, const bf16* __restrict__ vmat, int ld,
    const float* __restrict__ omega, bf16* __restrict__ CS,
    float* __restrict__ segtot) {
  const int tid = threadIdx.x;
  const int bh = blockIdx.y, b = bh >> 4, h = bh & 15;
  const int seg = blockIdx.x;
  const int s0 = seg * 512;
  __shared__ __align__(16) bf16 vs[512][64];   // XOR-swizzled, 64 KB
  __shared__ float kps[512][8];                // 16 KB
  __shared__ float oms[448];

  {
    const bf16* vb = vmat + ((size_t)(b * Sq + s0)) * ld + h * 64;
#pragma unroll
    for (int p = 0; p < 8; ++p) {
      const int row = p * 64 + (tid >> 3), c16 = (tid & 7) * 8;
      *(uint4*)&vs[row][c16 ^ ((row & 7) * 8)] =
          *(const uint4*)&vb[(size_t)row * ld + c16];
    }
  }
  if (tid < 448) oms[tid] = omega[tid];
  __syncthreads();

  {
    const int row = tid;
    const bf16* kr = kmat + ((size_t)(b * Sq + s0 + row)) * ld + h * 64;
    bf16x8 kv[8];
#pragma unroll
    for (int q = 0; q < 8; ++q) kv[q] = *(const bf16x8*)&kr[q * 8];
    float f[NB];
#pragma unroll
    for (int n = 0; n < NB; ++n) f[n] = 0.f;
#pragma unroll
    for (int d = 0; d < 64; ++d) {
      const float kd = (float)kv[d >> 3][d & 7];
#pragma unroll
      for (int n = 0; n < NB; ++n) f[n] += kd * oms[n * 64 + d];
    }
    float sum = 1e-6f, e[NB];
#pragma unroll
    for (int n = 0; n < NB; ++n) { e[n] = __expf(-0.5f * f[n] * f[n]); sum += e[n]; }
    const float inv = 1.f / sum;
#pragma unroll
    for (int n = 0; n < NB; ++n) kps[row][n] = e[n] * inv;
    kps[row][7] = 0.f;
  }
  __syncthreads();

  if (tid < CSW) {
    const int comp = tid;
    bf16* outb = CS + ((size_t)bh * NCH + seg * 128) * CSW;
    float r = 0.f;
    if (comp < 8) {
      for (int c = 0; c < 128; ++c) {
        if (comp < 7)
          r += kps[4*c][comp] + kps[4*c+1][comp] + kps[4*c+2][comp] + kps[4*c+3][comp];
        outb[(size_t)c * CSW + comp] = (bf16)r;
      }
    } else if (comp < 456) {
      const int n = (comp - 8) >> 6, d = (comp - 8) & 63;
      for (int c = 0; c < 128; ++c) {
#pragma unroll
        for (int i = 0; i < 4; ++i) {
          const int row = 4 * c + i;
          r += kps[row][n] * (float)vs[row][d ^ ((row & 7) * 8)];
        }
        outb[(size_t)c * CSW + comp] = (bf16)r;
      }
    } else {
      for (int c = 0; c < 128; ++c) outb[(size_t)c * CSW + comp] = (bf16)0.f;
    }
    segtot[((size_t)bh * 8 + seg) * CSW + comp] = r;
  }
}

// ---------------- Performer output (computes its own segment prefix) ----------------
__global__ __launch_bounds__(256) void perf_out(
    const bf16* __restrict__ qmat, int ldq, const float* __restrict__ omega,
    const bf16* __restrict__ CS, const float* __restrict__ segtot,
    bf16* __restrict__ attn) {
  const int tid = threadIdx.x;
  const int bh = blockIdx.y, b = bh >> 4, h = bh & 15;
  const int s0 = blockIdx.x * 128;
  const int cg0 = s0 >> 2;
  const int seg = cg0 >> 7;
  __shared__ __align__(16) float Ps[32 * CSW];
  __shared__ float qps[128][8];
  __shared__ float oms[NB * 64];
  __shared__ float offs[CSW];

  // exclusive prefix of segment totals (<= 7 rows of 464 f32)
  for (int c = tid; c < CSW; c += 256) {
    float o = 0.f;
    for (int ss = 0; ss < seg; ++ss) o += segtot[((size_t)bh * 8 + ss) * CSW + c];
    offs[c] = o;
  }
  if (tid < 224) { oms[tid] = omega[tid]; oms[tid + 224] = omega[tid + 224]; }
  __syncthreads();

  {
    const bf16* src = CS + ((size_t)bh * NCH + cg0) * CSW;
    for (int i = tid; i < 32 * CSW / 4; i += 256) {
      bf16x4 a4 = *(const bf16x4*)&src[(size_t)i * 4];
      const int c0 = (i % (CSW / 4)) * 4;
      f32x4 o;
#pragma unroll
      for (int e = 0; e < 4; ++e) o[e] = (float)a4[e] + offs[c0 + e];
      *(f32x4*)&Ps[i * 4] = o;
    }
  }
  __syncthreads();
  {
    const int p = tid >> 1, half = tid & 1;
    const bf16* qr = qmat + ((size_t)(b * Sq + s0 + p)) * ldq + h * 64 + half * 32;
    bf16x8 qv[4];
#pragma unroll
    for (int q = 0; q < 4; ++q) qv[q] = *(const bf16x8*)&qr[q * 8];
    float f[NB];
#pragma unroll
    for (int n = 0; n < NB; ++n) f[n] = 0.f;
#pragma unroll
    for (int d = 0; d < 32; ++d) {
      float qd = (float)qv[d >> 3][d & 7];
#pragma unroll
      for (int n = 0; n < NB; ++n) f[n] += qd * oms[n * 64 + half * 32 + d];
    }
    float sum = 1e-6f;
    float e[NB];
#pragma unroll
    for (int n = 0; n < NB; ++n) {
      float full = f[n] + __shfl_xor(f[n], 1);
      e[n] = __expf(-0.5f * full * full);
      sum += e[n];
    }
    float inv = 1.f / sum;
    if (half == 0) {
      float den = 1e-6f;
      const float* Pr = &Ps[(p >> 2) * CSW];
#pragma unroll
      for (int n = 0; n < NB; ++n) {
        float qn = e[n] * inv;
        qps[p][n] = qn;
        den += qn * Pr[n];
      }
      qps[p][7] = 1.f / den;
    }
  }
  __syncthreads();
  {
    const int d = tid & 63, w = tid >> 6;
    for (int qq = w; qq < 128; qq += 4) {
      const float* Pr = &Ps[(qq >> 2) * CSW + 8 + d];
      float num = 0.f;
#pragma unroll
      for (int n = 0; n < NB; ++n) num += qps[qq][n] * Pr[n * 64];
      attn[((size_t)(b * Sq + s0 + qq)) * Dm + h * 64 + d] = (bf16)(num * qps[qq][7]);
    }
  }
}

// ---------------------------------------------------------------------------
extern "C" void kernel_launch(void* const* d_in, const int* in_sizes, int n_in,
                              void* d_out, int out_size, void* d_ws, size_t ws_size,
                              hipStream_t stream) {
  const float* x    = (const float*)d_in[0];
  const float* lto  = (const float*)d_in[1];
  const float* w_s[4] = {(const float*)d_in[2], (const float*)d_in[3],
                         (const float*)d_in[4], (const float*)d_in[5]};
  const float* w_c[4] = {(const float*)d_in[6], (const float*)d_in[7],
                         (const float*)d_in[8], (const float*)d_in[9]};
  const float* omega_s = (const float*)d_in[10];
  const float* omega_c = (const float*)d_in[11];
  const float* w1 = (const float*)d_in[12];
  const float* b1 = (const float*)d_in[13];
  const float* w2 = (const float*)d_in[14];
  const float* b2 = (const float*)d_in[15];
  const float* ln_a[3] = {(const float*)d_in[16], (const float*)d_in[18], (const float*)d_in[20]};
  const float* ln_b[3] = {(const float*)d_in[17], (const float*)d_in[19], (const float*)d_in[21]};

  char* ws = (char*)d_ws;
  size_t off = 0;
  auto alloc = [&](size_t bytes) -> char* {
    char* p = ws + off;
    off += (bytes + 255) & ~(size_t)255;
    return p;
  };

  const size_t actB = (size_t)Mrows * Dm * sizeof(bf16);     // 16 MiB
  const size_t MB32 = (size_t)Mrows * 2048 * sizeof(bf16);   // 32 MiB

  bf16* wqkv = (bf16*)alloc((size_t)3072 * 1024 * 2);
  bf16* wo_sb = (bf16*)alloc((size_t)1024 * 1024 * 2);
  bf16* wq_cb = (bf16*)alloc((size_t)1024 * 1024 * 2);
  bf16* wkv  = (bf16*)alloc((size_t)2048 * 1024 * 2);
  bf16* wo_cb = (bf16*)alloc((size_t)1024 * 1024 * 2);
  bf16* w1b = (bf16*)alloc((size_t)Dff * Dm * 2);
  bf16* w2b = (bf16*)alloc((size_t)Dff * Dm * 2);
  bf16* xnb  = (bf16*)alloc(actB);
  char* pool = alloc((size_t)Mrows * Dff * 2);               // 64 MiB shared pool
  bf16* qkvb = (bf16*)pool;                                  // 48 MiB (phase 1)
  bf16* kvb  = (bf16*)pool;                                  // 32 MiB (phase 2)
  bf16* qb   = (bf16*)(pool + MB32);                         // 16 MiB (phase 2)
  bf16* hb   = (bf16*)pool;                                  // 64 MiB (phase 3)
  bf16* attnb= (bf16*)alloc(actB);
  bf16* x2b  = (bf16*)alloc(actB);
  bf16* ln1b = (bf16*)alloc(actB);
  float* lto2 = (float*)alloc((size_t)Mrows * Dm * 4);
  bf16*  CSb  = (bf16*)alloc((size_t)32 * NCH * CSW * 2);
  float* stb  = (float*)alloc((size_t)32 * 8 * CSW * 4);
  bf16* fnb = xnb;   // xnb dead after QKV_s GEMM

  // ---- batched weight conversion ----
  {
    CvtA a;
    const float* srcs[10] = {w_s[0], w_s[1], w_s[2], w_s[3], w_c[0],
                             w_c[1], w_c[2], w_c[3], w1, w2};
    bf16* dsts[10] = {wqkv, wqkv + 1048576, wqkv + 2097152, wo_sb, wq_cb,
                      wkv, wkv + 1048576, wo_cb, w1b, w2b};
    const int SM = 262144, LG = 1048576;
    int st = 0;
    for (int i = 0; i < 10; ++i) {
      a.s[i] = srcs[i]; a.d[i] = dsts[i]; a.start[i] = st;
      st += (i < 8) ? SM : LG;
    }
    a.start[10] = st;
    cvt10<<<st / 256, 256, 0, stream>>>(a);
  }

  dim3 gperf(Sq / 128, Bq * 16);
  dim3 gseg(8, Bq * 16);
  const int gQKV = (Mrows / 128) * (3072 / 128);   // 1536
  const int gKV  = (Mrows / 128) * (2048 / 128);   // 1024
  const int gFF1 = (Mrows / 128) * (4096 / 128);   // 2048
  const int gN1k = (Mrows / 128) * (1024 / 128);   // 512

  // --- self performer on x ---
  ln_kernel<<<Mrows, 256, 0, stream>>>(x, ln_a[0], ln_b[0], xnb);
  gemm128<0><<<gQKV, 256, 0, stream>>>(xnb, wqkv, Mrows, 3072, 1024, nullptr, nullptr, nullptr, qkvb);
  perf_cs<<<gseg, 512, 0, stream>>>(qkvb + 1024, qkvb + 2048, 3072, omega_s, CSb, stb);
  perf_out<<<gperf, 256, 0, stream>>>(qkvb, 3072, omega_s, CSb, stb, attnb);
  gemm128<1><<<gN1k, 256, 0, stream>>>(attnb, wo_sb, Mrows, 1024, 1024, nullptr, x, nullptr, x2b);

  // --- cross performer: q from LN(lto), k/v from updated x ---
  ln_kernel<<<Mrows, 256, 0, stream>>>(lto, ln_a[1], ln_b[1], ln1b);
  gemm128<0><<<gN1k, 256, 0, stream>>>(ln1b, wq_cb, Mrows, 1024, 1024, nullptr, nullptr, nullptr, qb);
  gemm128<0><<<gKV, 256, 0, stream>>>(x2b, wkv, Mrows, 2048, 1024, nullptr, nullptr, nullptr, kvb);
  perf_cs<<<gseg, 512, 0, stream>>>(kvb, kvb + 1024, 2048, omega_c, CSb, stb);
  perf_out<<<gperf, 256, 0, stream>>>(qb, 1024, omega_c, CSb, stb, attnb);
  gemm128<2><<<gN1k, 256, 0, stream>>>(attnb, wo_cb, Mrows, 1024, 1024, nullptr, lto, lto2, nullptr);

  // --- FFN ---
  ln_kernel<<<Mrows, 256, 0, stream>>>(lto2, ln_a[2], ln_b[2], fnb);
  gemm128<3><<<gFF1, 256, 0, stream>>>(fnb, w1b, Mrows, 4096, 1024, b1, nullptr, nullptr, hb);
  gemm128<4><<<gN1k, 256, 0, stream>>>(hb, w2b, Mrows, 1024, 4096, b2, lto2, (float*)d_out, nullptr);
}